// Round 1
// baseline (1505.462 us; speedup 1.0000x reference)
//
#include <hip/hip_runtime.h>

typedef unsigned short u16;
using short8 = __attribute__((ext_vector_type(8))) short;
using f32x4  = __attribute__((ext_vector_type(4))) float;

#define NLAYER 4
#define DMODEL 1024
#define DSTATE 16
#define DINNER 2048
#define DTRANK 64
#define SEQL   1024
#define NBATCH 2
#define MTOK   2048   /* NBATCH*SEQL */

__device__ __forceinline__ u16 f2bf(float f) {
  union { float f; unsigned int u; } cv; cv.f = f;
  return (u16)((cv.u + 0x7FFFu + ((cv.u >> 16) & 1u)) >> 16);
}

// ---------------- weight conversion ----------------
__global__ __launch_bounds__(256) void f32_to_bf16_k(const float* __restrict__ src,
                                                     u16* __restrict__ dst, int n) {
  int i4 = (blockIdx.x * 256 + threadIdx.x) * 4;
  if (i4 >= n) return;
  float4 v = *(const float4*)&src[i4];
  ushort4 o; o.x = f2bf(v.x); o.y = f2bf(v.y); o.z = f2bf(v.z); o.w = f2bf(v.w);
  *(ushort4*)&dst[i4] = o;
}

// x_proj_w (96 x 2048) -> padded (128 x 2048) bf16
__global__ __launch_bounds__(256) void cvt_pad_xproj_k(const float* __restrict__ src,
                                                       u16* __restrict__ dst) {
  int i4 = (blockIdx.x * 256 + threadIdx.x) * 4;   // total 128*2048
  int row = i4 >> 11, col = i4 & 2047;
  float4 v = make_float4(0.f, 0.f, 0.f, 0.f);
  if (row < 96) v = *(const float4*)&src[row * 2048 + col];
  ushort4 o; o.x = f2bf(v.x); o.y = f2bf(v.y); o.z = f2bf(v.z); o.w = f2bf(v.w);
  *(ushort4*)&dst[i4] = o;
}

// xdbl (2048 x 128) cols 0..63 -> bf16 (2048 x 64)
__global__ __launch_bounds__(256) void cvt_dtin_k(const float* __restrict__ xdbl,
                                                  u16* __restrict__ dtin) {
  int i4 = (blockIdx.x * 256 + threadIdx.x) * 4;   // total 2048*64
  int m = i4 >> 6, r = i4 & 63;
  float4 v = *(const float4*)&xdbl[m * 128 + r];
  ushort4 o; o.x = f2bf(v.x); o.y = f2bf(v.y); o.z = f2bf(v.z); o.w = f2bf(v.w);
  *(ushort4*)&dtin[i4] = o;
}

// ---------------- LayerNorm -> bf16 (row = 1024) ----------------
__global__ __launch_bounds__(256) void ln_to_bf16_k(const float* __restrict__ X,
    const float* __restrict__ w, const float* __restrict__ b, u16* __restrict__ out) {
  int row = blockIdx.x, tid = threadIdx.x;
  const float* x = X + (size_t)row * 1024;
  float4 v = ((const float4*)x)[tid];
  float s = v.x + v.y + v.z + v.w;
  float q = v.x*v.x + v.y*v.y + v.z*v.z + v.w*v.w;
  for (int o = 32; o; o >>= 1) { s += __shfl_down(s, o); q += __shfl_down(q, o); }
  __shared__ float sb[4], qb[4];
  int wv = tid >> 6, lane = tid & 63;
  if (lane == 0) { sb[wv] = s; qb[wv] = q; }
  __syncthreads();
  s = sb[0] + sb[1] + sb[2] + sb[3];
  q = qb[0] + qb[1] + qb[2] + qb[3];
  float mean = s * (1.f / 1024.f);
  float var  = q * (1.f / 1024.f) - mean * mean;
  float rstd = rsqrtf(var + 1e-5f);
  float4 wv4 = ((const float4*)w)[tid];
  float4 bv4 = ((const float4*)b)[tid];
  ushort4 o4;
  o4.x = f2bf((v.x - mean) * rstd * wv4.x + bv4.x);
  o4.y = f2bf((v.y - mean) * rstd * wv4.y + bv4.y);
  o4.z = f2bf((v.z - mean) * rstd * wv4.z + bv4.z);
  o4.w = f2bf((v.w - mean) * rstd * wv4.w + bv4.w);
  ((ushort4*)(out + (size_t)row * 1024))[tid] = o4;
}

// ---------------- MFMA GEMM: C[M,N] = A[M,K] * W[N,K]^T ----------------
// 128x128 tile, 4 waves (each 64x64 = 4x4 frags of 16x16x32), BK=32.
__device__ __forceinline__ void stage_tile(const u16* G, int ld, int row0, int k0,
                                           u16* S, int tid) {
  int w = tid >> 6;
#pragma unroll
  for (int j = 0; j < 2; ++j) {
    int t = tid + j * 256;
    int r = t >> 2;
    int c = (t & 3) << 3;
    const u16* g = G + (size_t)(row0 + r) * ld + (k0 + c);
    u16* s = S + w * 512 + j * 2048;  // wave-uniform base; HW adds lane*16B
    __builtin_amdgcn_global_load_lds((const __attribute__((address_space(1))) void*)g,
                                     (__attribute__((address_space(3))) void*)s,
                                     16, 0, 0);
  }
}

// EPI: 0 = plain store, 2 = softplus(bias add), 3 = atomicAdd
template<int EPI>
__global__ __launch_bounds__(256) void gemm_bt(const u16* __restrict__ A,
    const u16* __restrict__ Bw, float* __restrict__ C, const float* __restrict__ bias,
    int lda, int ldb, int ldc, int kchunk) {
  __shared__ u16 As[128 * 32];
  __shared__ u16 Bs[128 * 32];
  int tid = threadIdx.x;
  int bm = blockIdx.x, bn = blockIdx.y;
  int kb = blockIdx.z * kchunk, ke = kb + kchunk;
  int lane = tid & 63, w = tid >> 6;
  int wr = (w >> 1) * 64, wc = (w & 1) * 64;
  int fr = lane & 15;
  int kg = (lane >> 4) * 8;
  f32x4 acc[4][4] = {};
  for (int k0 = kb; k0 < ke; k0 += 32) {
    __syncthreads();
    stage_tile(A, lda, bm * 128, k0, As, tid);
    stage_tile(Bw, ldb, bn * 128, k0, Bs, tid);
    __syncthreads();
    short8 a[4], b[4];
#pragma unroll
    for (int mf = 0; mf < 4; ++mf)
      a[mf] = *(const short8*)&As[(wr + mf * 16 + fr) * 32 + kg];
#pragma unroll
    for (int nf = 0; nf < 4; ++nf)
      b[nf] = *(const short8*)&Bs[(wc + nf * 16 + fr) * 32 + kg];
#pragma unroll
    for (int mf = 0; mf < 4; ++mf)
#pragma unroll
      for (int nf = 0; nf < 4; ++nf)
        acc[mf][nf] = __builtin_amdgcn_mfma_f32_16x16x32_bf16(a[mf], b[nf], acc[mf][nf], 0, 0, 0);
  }
  int r0 = bm * 128 + wr + (lane >> 4) * 4;
  int c0 = bn * 128 + wc + (lane & 15);
#pragma unroll
  for (int mf = 0; mf < 4; ++mf) {
#pragma unroll
    for (int nf = 0; nf < 4; ++nf) {
#pragma unroll
      for (int r = 0; r < 4; ++r) {
        int gr = r0 + mf * 16 + r;
        int gc = c0 + nf * 16;
        float v = acc[mf][nf][r];
        size_t idx = (size_t)gr * ldc + gc;
        if (EPI == 0) {
          C[idx] = v;
        } else if (EPI == 2) {
          v += bias[gc];
          v = (v > 20.f) ? v : log1pf(__expf(v));
          C[idx] = v;
        } else {
          atomicAdd(&C[idx], v);
        }
      }
    }
  }
}

// ---------------- causal depthwise conv (K=4) + SiLU ----------------
__global__ __launch_bounds__(256) void conv_silu_k(const float* __restrict__ xz,
    const float* __restrict__ cw, const float* __restrict__ cb,
    float* __restrict__ xs, u16* __restrict__ xsb) {
  int idx = blockIdx.x * 256 + threadIdx.x;  // 2048 * 512
  int m = idx >> 9;
  int d = (idx & 511) << 2;
  int t = m & 1023;
  float4 w0 = *(const float4*)&cw[(d + 0) * 4];
  float4 w1 = *(const float4*)&cw[(d + 1) * 4];
  float4 w2 = *(const float4*)&cw[(d + 2) * 4];
  float4 w3 = *(const float4*)&cw[(d + 3) * 4];
  float4 acc = *(const float4*)&cb[d];
#pragma unroll
  for (int j = 0; j < 4; ++j) {
    int tt = t - 3 + j;
    if (tt >= 0) {
      float4 xv = *(const float4*)&xz[(size_t)(m - 3 + j) * 4096 + d];
      acc.x += xv.x * ((const float*)&w0)[j];
      acc.y += xv.y * ((const float*)&w1)[j];
      acc.z += xv.z * ((const float*)&w2)[j];
      acc.w += xv.w * ((const float*)&w3)[j];
    }
  }
  float4 o;
  o.x = acc.x / (1.f + __expf(-acc.x));
  o.y = acc.y / (1.f + __expf(-acc.y));
  o.z = acc.z / (1.f + __expf(-acc.z));
  o.w = acc.w / (1.f + __expf(-acc.w));
  *(float4*)&xs[(size_t)m * 2048 + d] = o;
  ushort4 ob; ob.x = f2bf(o.x); ob.y = f2bf(o.y); ob.z = f2bf(o.z); ob.w = f2bf(o.w);
  *(ushort4*)&xsb[(size_t)m * 2048 + d] = ob;
}

// ---------------- selective scan + D skip + z-gating -> bf16 ----------------
// block: 256 threads = 16 channels x 16 states; grid: 2 batches * 128 channel-groups
__global__ __launch_bounds__(256) void scan_k(const float* __restrict__ xs,
    const float* __restrict__ dt, const float* __restrict__ xdbl,
    const float* __restrict__ Alog, const float* __restrict__ Dv,
    const float* __restrict__ xz, u16* __restrict__ yg) {
  int tid = threadIdx.x;
  int c = tid >> 4, n = tid & 15;
  int b = blockIdx.x >> 7;
  int d0 = (blockIdx.x & 127) * 16;
  int d = d0 + c;
  float A = -__expf(Alog[d * 16 + n]);
  float Dvd = Dv[d];
  __shared__ float dts[64][16], xss[64][16], Bsh[64][16], Csh[64][16], zsh[64][16], ysh[64][16];
  float h = 0.f;
  int mbase = b * 1024;
  for (int t0 = 0; t0 < 1024; t0 += 64) {
    __syncthreads();
    for (int i = tid; i < 1024; i += 256) {
      int tt = i >> 4, cc = i & 15;
      int m = mbase + t0 + tt;
      dts[tt][cc] = dt[(size_t)m * 2048 + d0 + cc];
      xss[tt][cc] = xs[(size_t)m * 2048 + d0 + cc];
      Bsh[tt][cc] = xdbl[m * 128 + 64 + cc];
      Csh[tt][cc] = xdbl[m * 128 + 80 + cc];
      zsh[tt][cc] = xz[(size_t)m * 4096 + 2048 + d0 + cc];
    }
    __syncthreads();
    for (int tt = 0; tt < 64; ++tt) {
      float dtv = dts[tt][c];
      float xv  = xss[tt][c];
      float da  = __expf(dtv * A);
      float bv  = dtv * Bsh[tt][n] * xv;
      h = fmaf(da, h, bv);
      float contrib = h * Csh[tt][n];
      contrib += __shfl_xor(contrib, 1);
      contrib += __shfl_xor(contrib, 2);
      contrib += __shfl_xor(contrib, 4);
      contrib += __shfl_xor(contrib, 8);
      if (n == 0) ysh[tt][c] = contrib + xv * Dvd;
    }
    __syncthreads();
    for (int i = tid; i < 1024; i += 256) {
      int tt = i >> 4, cc = i & 15;
      int m = mbase + t0 + tt;
      float z = zsh[tt][cc];
      float sz = z / (1.f + __expf(-z));
      yg[(size_t)m * 2048 + d0 + cc] = f2bf(ysh[tt][cc] * sz);
    }
  }
}

// ---------------- head ----------------
__global__ __launch_bounds__(256) void final_ln_last_k(const float* __restrict__ xb,
    const float* __restrict__ w, const float* __restrict__ b, float* __restrict__ out) {
  int bb = blockIdx.x, tid = threadIdx.x;
  const float* x = xb + (size_t)(bb * 1024 + 1023) * 1024;
  float4 v = ((const float4*)x)[tid];
  float s = v.x + v.y + v.z + v.w;
  float q = v.x*v.x + v.y*v.y + v.z*v.z + v.w*v.w;
  for (int o = 32; o; o >>= 1) { s += __shfl_down(s, o); q += __shfl_down(q, o); }
  __shared__ float sb[4], qb[4];
  int wv = tid >> 6, lane = tid & 63;
  if (lane == 0) { sb[wv] = s; qb[wv] = q; }
  __syncthreads();
  s = sb[0] + sb[1] + sb[2] + sb[3];
  q = qb[0] + qb[1] + qb[2] + qb[3];
  float mean = s * (1.f / 1024.f);
  float rstd = rsqrtf(q * (1.f / 1024.f) - mean * mean + 1e-5f);
  float4 wv4 = ((const float4*)w)[tid];
  float4 bv4 = ((const float4*)b)[tid];
  float4 o;
  o.x = (v.x - mean) * rstd * wv4.x + bv4.x;
  o.y = (v.y - mean) * rstd * wv4.y + bv4.y;
  o.z = (v.z - mean) * rstd * wv4.z + bv4.z;
  o.w = (v.w - mean) * rstd * wv4.w + bv4.w;
  ((float4*)(out + bb * 1024))[tid] = o;
}

__global__ __launch_bounds__(256) void gemv_head1_k(const float* __restrict__ X,
    const float* __restrict__ W, const float* __restrict__ bias, float* __restrict__ out) {
  int gw = (blockIdx.x * 256 + threadIdx.x) >> 6;  // 0..4095
  int lane = threadIdx.x & 63;
  int b = gw >> 11, j = gw & 2047;
  const float* x = X + b * 1024;
  const float* w = W + (size_t)j * 1024;
  float s = 0.f;
#pragma unroll
  for (int q = 0; q < 4; ++q) {
    int col = q * 256 + lane * 4;
    float4 xv = *(const float4*)&x[col];
    float4 wv = *(const float4*)&w[col];
    s += xv.x*wv.x + xv.y*wv.y + xv.z*wv.z + xv.w*wv.w;
  }
  for (int o = 32; o; o >>= 1) s += __shfl_down(s, o);
  if (lane == 0) out[gw] = s + bias[j];
}

__global__ __launch_bounds__(256) void ln_gelu_k(const float* __restrict__ X,
    const float* __restrict__ w, const float* __restrict__ b, float* __restrict__ out) {
  int row = blockIdx.x, tid = threadIdx.x;
  const float* x = X + (size_t)row * 2048;
  float4 v0 = ((const float4*)x)[tid];
  float4 v1 = ((const float4*)x)[tid + 256];
  float s = v0.x+v0.y+v0.z+v0.w + v1.x+v1.y+v1.z+v1.w;
  float q = v0.x*v0.x+v0.y*v0.y+v0.z*v0.z+v0.w*v0.w
          + v1.x*v1.x+v1.y*v1.y+v1.z*v1.z+v1.w*v1.w;
  for (int o = 32; o; o >>= 1) { s += __shfl_down(s, o); q += __shfl_down(q, o); }
  __shared__ float sb[4], qb[4];
  int wv = tid >> 6, lane = tid & 63;
  if (lane == 0) { sb[wv] = s; qb[wv] = q; }
  __syncthreads();
  s = sb[0] + sb[1] + sb[2] + sb[3];
  q = qb[0] + qb[1] + qb[2] + qb[3];
  float mean = s * (1.f / 2048.f);
  float rstd = rsqrtf(q * (1.f / 2048.f) - mean * mean + 1e-5f);
  float* o0 = out + (size_t)row * 2048;
#pragma unroll
  for (int h = 0; h < 2; ++h) {
    float4 v = h ? v1 : v0;
    int c0 = tid * 4 + h * 1024;
    float4 wv4 = *(const float4*)&w[c0];
    float4 bv4 = *(const float4*)&b[c0];
    float4 g;
    g.x = (v.x - mean) * rstd * wv4.x + bv4.x;
    g.y = (v.y - mean) * rstd * wv4.y + bv4.y;
    g.z = (v.z - mean) * rstd * wv4.z + bv4.z;
    g.w = (v.w - mean) * rstd * wv4.w + bv4.w;
    g.x = 0.5f * g.x * (1.f + erff(g.x * 0.70710678f));
    g.y = 0.5f * g.y * (1.f + erff(g.y * 0.70710678f));
    g.z = 0.5f * g.z * (1.f + erff(g.z * 0.70710678f));
    g.w = 0.5f * g.w * (1.f + erff(g.w * 0.70710678f));
    *(float4*)&o0[c0] = g;
  }
}

__global__ __launch_bounds__(256) void gemv_head2_k(const float* __restrict__ X,
    const float* __restrict__ W, const float* __restrict__ bias, float* __restrict__ out) {
  int gw = (blockIdx.x * 256 + threadIdx.x) >> 6;  // 0..1999
  int lane = threadIdx.x & 63;
  int b = (gw >= 1000) ? 1 : 0;
  int j = gw - b * 1000;
  const float* x = X + b * 2048;
  const float* w = W + (size_t)j * 2048;
  float s = 0.f;
#pragma unroll
  for (int q = 0; q < 8; ++q) {
    int col = q * 256 + lane * 4;
    float4 xv = *(const float4*)&x[col];
    float4 wv = *(const float4*)&w[col];
    s += xv.x*wv.x + xv.y*wv.y + xv.z*wv.z + xv.w*wv.w;
  }
  for (int o = 32; o; o >>= 1) s += __shfl_down(s, o);
  if (lane == 0) out[gw] = s + bias[j];
}

// ---------------- launch ----------------
extern "C" void kernel_launch(void* const* d_in, const int* in_sizes, int n_in,
                              void* d_out, int out_size, void* d_ws, size_t ws_size,
                              hipStream_t stream) {
  const float* x_in = (const float*)d_in[0];
  const float* lnw  = (const float*)d_in[1];
  const float* lnb  = (const float*)d_in[2];
  const float* ipw  = (const float*)d_in[3];
  const float* cw   = (const float*)d_in[4];
  const float* cb   = (const float*)d_in[5];
  const float* xpw  = (const float*)d_in[6];
  const float* dpw  = (const float*)d_in[7];
  const float* dpb  = (const float*)d_in[8];
  const float* Alog = (const float*)d_in[9];
  const float* Dv   = (const float*)d_in[10];
  const float* opw  = (const float*)d_in[11];
  const float* fnw  = (const float*)d_in[12];
  const float* fnb  = (const float*)d_in[13];
  const float* h1w  = (const float*)d_in[14];
  const float* h1b  = (const float*)d_in[15];
  const float* hlnw = (const float*)d_in[16];
  const float* hlnb = (const float*)d_in[17];
  const float* h2w  = (const float*)d_in[18];
  const float* h2b  = (const float*)d_in[19];
  float* out = (float*)d_out;

  char* ws = (char*)d_ws;
  size_t off = 0;
  auto alloc = [&](size_t bytes) -> void* {
    void* p = ws + off; off += (bytes + 255) & ~(size_t)255; return p;
  };
  float* x_buf    = (float*)alloc((size_t)MTOK * DMODEL * 4);
  u16*   xn_bf    = (u16*)  alloc((size_t)MTOK * DMODEL * 2);
  float* xz       = (float*)alloc((size_t)MTOK * 2 * DINNER * 4);
  float* xs       = (float*)alloc((size_t)MTOK * DINNER * 4);
  u16*   xs_bf    = (u16*)  alloc((size_t)MTOK * DINNER * 2);
  float* xdbl     = (float*)alloc((size_t)MTOK * 128 * 4);
  u16*   dtin_bf  = (u16*)  alloc((size_t)MTOK * DTRANK * 2);
  float* dtbuf    = (float*)alloc((size_t)MTOK * DINNER * 4);
  u16*   yg_bf    = (u16*)  alloc((size_t)MTOK * DINNER * 2);
  u16*   w_ip     = (u16*)  alloc((size_t)2 * DINNER * DMODEL * 2);
  u16*   w_xp     = (u16*)  alloc((size_t)128 * DINNER * 2);
  u16*   w_dt     = (u16*)  alloc((size_t)DINNER * DTRANK * 2);
  u16*   w_op     = (u16*)  alloc((size_t)DMODEL * DINNER * 2);
  float* lastn    = (float*)alloc(2 * 1024 * 4);
  float* hpre     = (float*)alloc(2 * 2048 * 4);
  float* hbuf     = (float*)alloc(2 * 2048 * 4);

  hipMemcpyAsync(x_buf, x_in, (size_t)MTOK * DMODEL * 4, hipMemcpyDeviceToDevice, stream);

  for (int i = 0; i < NLAYER; ++i) {
    f32_to_bf16_k<<<4096, 256, 0, stream>>>(ipw + (size_t)i * 2 * DINNER * DMODEL, w_ip, 2 * DINNER * DMODEL);
    cvt_pad_xproj_k<<<256, 256, 0, stream>>>(xpw + (size_t)i * 96 * DINNER, w_xp);
    f32_to_bf16_k<<<128, 256, 0, stream>>>(dpw + (size_t)i * DINNER * DTRANK, w_dt, DINNER * DTRANK);
    f32_to_bf16_k<<<2048, 256, 0, stream>>>(opw + (size_t)i * DMODEL * DINNER, w_op, DMODEL * DINNER);
    ln_to_bf16_k<<<MTOK, 256, 0, stream>>>(x_buf, lnw + i * DMODEL, lnb + i * DMODEL, xn_bf);
    { dim3 g(16, 32, 1);
      gemm_bt<0><<<g, 256, 0, stream>>>(xn_bf, w_ip, xz, nullptr, 1024, 1024, 4096, 1024); }
    conv_silu_k<<<4096, 256, 0, stream>>>(xz, cw + (size_t)i * DINNER * 4, cb + i * DINNER, xs, xs_bf);
    hipMemsetAsync(xdbl, 0, (size_t)MTOK * 128 * 4, stream);
    { dim3 g(16, 1, 8);
      gemm_bt<3><<<g, 256, 0, stream>>>(xs_bf, w_xp, xdbl, nullptr, 2048, 2048, 128, 256); }
    cvt_dtin_k<<<128, 256, 0, stream>>>(xdbl, dtin_bf);
    { dim3 g(16, 16, 1);
      gemm_bt<2><<<g, 256, 0, stream>>>(dtin_bf, w_dt, dtbuf, dpb + i * DINNER, 64, 64, 2048, 64); }
    scan_k<<<256, 256, 0, stream>>>(xs, dtbuf, xdbl, Alog + (size_t)i * DINNER * DSTATE,
                                    Dv + i * DINNER, xz, yg_bf);
    { dim3 g(16, 8, 2);
      gemm_bt<3><<<g, 256, 0, stream>>>(yg_bf, w_op, x_buf, nullptr, 2048, 2048, 1024, 1024); }
  }
  final_ln_last_k<<<2, 256, 0, stream>>>(x_buf, fnw, fnb, lastn);
  gemv_head1_k<<<1024, 256, 0, stream>>>(lastn, h1w, h1b, hpre);
  ln_gelu_k<<<2, 256, 0, stream>>>(hpre, hlnw, hlnb, hbuf);
  gemv_head2_k<<<500, 256, 0, stream>>>(hbuf, h2w, h2b, out);
  (void)in_sizes; (void)n_in; (void)out_size; (void)ws_size;
}

// Round 2
// 1034.029 us; speedup vs baseline: 1.4559x; 1.4559x over previous
//
#include <hip/hip_runtime.h>

typedef unsigned short u16;
using short8 = __attribute__((ext_vector_type(8))) short;
using f32x4  = __attribute__((ext_vector_type(4))) float;

#define NLAYER 4
#define DMODEL 1024
#define DSTATE 16
#define DINNER 2048
#define DTRANK 64
#define SEQL   1024
#define NBATCH 2
#define MTOK   2048   /* NBATCH*SEQL */
#define NCH    32     /* scan chunks per sequence */
#define CLEN   32     /* timesteps per chunk: NCH*CLEN == SEQL */

__device__ __forceinline__ u16 f2bf(float f) {
  union { float f; unsigned int u; } cv; cv.f = f;
  return (u16)((cv.u + 0x7FFFu + ((cv.u >> 16) & 1u)) >> 16);
}

// ---------------- weight conversion ----------------
__global__ __launch_bounds__(256) void f32_to_bf16_k(const float* __restrict__ src,
                                                     u16* __restrict__ dst, int n) {
  int i4 = (blockIdx.x * 256 + threadIdx.x) * 4;
  if (i4 >= n) return;
  float4 v = *(const float4*)&src[i4];
  ushort4 o; o.x = f2bf(v.x); o.y = f2bf(v.y); o.z = f2bf(v.z); o.w = f2bf(v.w);
  *(ushort4*)&dst[i4] = o;
}

// x_proj_w (96 x 2048) -> padded (128 x 2048) bf16
__global__ __launch_bounds__(256) void cvt_pad_xproj_k(const float* __restrict__ src,
                                                       u16* __restrict__ dst) {
  int i4 = (blockIdx.x * 256 + threadIdx.x) * 4;   // total 128*2048
  int row = i4 >> 11, col = i4 & 2047;
  float4 v = make_float4(0.f, 0.f, 0.f, 0.f);
  if (row < 96) v = *(const float4*)&src[row * 2048 + col];
  ushort4 o; o.x = f2bf(v.x); o.y = f2bf(v.y); o.z = f2bf(v.z); o.w = f2bf(v.w);
  *(ushort4*)&dst[i4] = o;
}

// xdbl (2048 x 128) cols 0..63 -> bf16 (2048 x 64)
__global__ __launch_bounds__(256) void cvt_dtin_k(const float* __restrict__ xdbl,
                                                  u16* __restrict__ dtin) {
  int i4 = (blockIdx.x * 256 + threadIdx.x) * 4;   // total 2048*64
  int m = i4 >> 6, r = i4 & 63;
  float4 v = *(const float4*)&xdbl[m * 128 + r];
  ushort4 o; o.x = f2bf(v.x); o.y = f2bf(v.y); o.z = f2bf(v.z); o.w = f2bf(v.w);
  *(ushort4*)&dtin[i4] = o;
}

// ---------------- LayerNorm -> bf16 (row = 1024) ----------------
__global__ __launch_bounds__(256) void ln_to_bf16_k(const float* __restrict__ X,
    const float* __restrict__ w, const float* __restrict__ b, u16* __restrict__ out) {
  int row = blockIdx.x, tid = threadIdx.x;
  const float* x = X + (size_t)row * 1024;
  float4 v = ((const float4*)x)[tid];
  float s = v.x + v.y + v.z + v.w;
  float q = v.x*v.x + v.y*v.y + v.z*v.z + v.w*v.w;
  for (int o = 32; o; o >>= 1) { s += __shfl_down(s, o); q += __shfl_down(q, o); }
  __shared__ float sb[4], qb[4];
  int wv = tid >> 6, lane = tid & 63;
  if (lane == 0) { sb[wv] = s; qb[wv] = q; }
  __syncthreads();
  s = sb[0] + sb[1] + sb[2] + sb[3];
  q = qb[0] + qb[1] + qb[2] + qb[3];
  float mean = s * (1.f / 1024.f);
  float var  = q * (1.f / 1024.f) - mean * mean;
  float rstd = rsqrtf(var + 1e-5f);
  float4 wv4 = ((const float4*)w)[tid];
  float4 bv4 = ((const float4*)b)[tid];
  ushort4 o4;
  o4.x = f2bf((v.x - mean) * rstd * wv4.x + bv4.x);
  o4.y = f2bf((v.y - mean) * rstd * wv4.y + bv4.y);
  o4.z = f2bf((v.z - mean) * rstd * wv4.z + bv4.z);
  o4.w = f2bf((v.w - mean) * rstd * wv4.w + bv4.w);
  ((ushort4*)(out + (size_t)row * 1024))[tid] = o4;
}

// ---------------- MFMA GEMM: C[M,N] = A[M,K] * W[N,K]^T ----------------
__device__ __forceinline__ void stage_tile(const u16* G, int ld, int row0, int k0,
                                           u16* S, int tid) {
  int w = tid >> 6;
#pragma unroll
  for (int j = 0; j < 2; ++j) {
    int t = tid + j * 256;
    int r = t >> 2;
    int c = (t & 3) << 3;
    const u16* g = G + (size_t)(row0 + r) * ld + (k0 + c);
    u16* s = S + w * 512 + j * 2048;  // wave-uniform base; HW adds lane*16B
    __builtin_amdgcn_global_load_lds((const __attribute__((address_space(1))) void*)g,
                                     (__attribute__((address_space(3))) void*)s,
                                     16, 0, 0);
  }
}

// EPI: 0 = plain store, 2 = softplus(bias add), 3 = atomicAdd
template<int EPI>
__global__ __launch_bounds__(256) void gemm_bt(const u16* __restrict__ A,
    const u16* __restrict__ Bw, float* __restrict__ C, const float* __restrict__ bias,
    int lda, int ldb, int ldc, int kchunk) {
  __shared__ u16 As[128 * 32];
  __shared__ u16 Bs[128 * 32];
  int tid = threadIdx.x;
  int bm = blockIdx.x, bn = blockIdx.y;
  int kb = blockIdx.z * kchunk, ke = kb + kchunk;
  int lane = tid & 63, w = tid >> 6;
  int wr = (w >> 1) * 64, wc = (w & 1) * 64;
  int fr = lane & 15;
  int kg = (lane >> 4) * 8;
  f32x4 acc[4][4] = {};
  for (int k0 = kb; k0 < ke; k0 += 32) {
    __syncthreads();
    stage_tile(A, lda, bm * 128, k0, As, tid);
    stage_tile(Bw, ldb, bn * 128, k0, Bs, tid);
    __syncthreads();
    short8 a[4], b[4];
#pragma unroll
    for (int mf = 0; mf < 4; ++mf)
      a[mf] = *(const short8*)&As[(wr + mf * 16 + fr) * 32 + kg];
#pragma unroll
    for (int nf = 0; nf < 4; ++nf)
      b[nf] = *(const short8*)&Bs[(wc + nf * 16 + fr) * 32 + kg];
#pragma unroll
    for (int mf = 0; mf < 4; ++mf)
#pragma unroll
      for (int nf = 0; nf < 4; ++nf)
        acc[mf][nf] = __builtin_amdgcn_mfma_f32_16x16x32_bf16(a[mf], b[nf], acc[mf][nf], 0, 0, 0);
  }
  int r0 = bm * 128 + wr + (lane >> 4) * 4;
  int c0 = bn * 128 + wc + (lane & 15);
#pragma unroll
  for (int mf = 0; mf < 4; ++mf) {
#pragma unroll
    for (int nf = 0; nf < 4; ++nf) {
#pragma unroll
      for (int r = 0; r < 4; ++r) {
        int gr = r0 + mf * 16 + r;
        int gc = c0 + nf * 16;
        float v = acc[mf][nf][r];
        size_t idx = (size_t)gr * ldc + gc;
        if (EPI == 0) {
          C[idx] = v;
        } else if (EPI == 2) {
          v += bias[gc];
          v = (v > 20.f) ? v : log1pf(__expf(v));
          C[idx] = v;
        } else {
          atomicAdd(&C[idx], v);
        }
      }
    }
  }
}

// ---------------- causal depthwise conv (K=4) + SiLU ----------------
__global__ __launch_bounds__(256) void conv_silu_k(const float* __restrict__ xz,
    const float* __restrict__ cw, const float* __restrict__ cb,
    float* __restrict__ xs, u16* __restrict__ xsb) {
  int idx = blockIdx.x * 256 + threadIdx.x;  // 2048 * 512
  int m = idx >> 9;
  int d = (idx & 511) << 2;
  int t = m & 1023;
  float4 w0 = *(const float4*)&cw[(d + 0) * 4];
  float4 w1 = *(const float4*)&cw[(d + 1) * 4];
  float4 w2 = *(const float4*)&cw[(d + 2) * 4];
  float4 w3 = *(const float4*)&cw[(d + 3) * 4];
  float4 acc = *(const float4*)&cb[d];
#pragma unroll
  for (int j = 0; j < 4; ++j) {
    int tt = t - 3 + j;
    if (tt >= 0) {
      float4 xv = *(const float4*)&xz[(size_t)(m - 3 + j) * 4096 + d];
      acc.x += xv.x * ((const float*)&w0)[j];
      acc.y += xv.y * ((const float*)&w1)[j];
      acc.z += xv.z * ((const float*)&w2)[j];
      acc.w += xv.w * ((const float*)&w3)[j];
    }
  }
  float4 o;
  o.x = acc.x / (1.f + __expf(-acc.x));
  o.y = acc.y / (1.f + __expf(-acc.y));
  o.z = acc.z / (1.f + __expf(-acc.z));
  o.w = acc.w / (1.f + __expf(-acc.w));
  *(float4*)&xs[(size_t)m * 2048 + d] = o;
  ushort4 ob; ob.x = f2bf(o.x); ob.y = f2bf(o.y); ob.z = f2bf(o.z); ob.w = f2bf(o.w);
  *(ushort4*)&xsb[(size_t)m * 2048 + d] = ob;
}

// ---------------- chunked selective scan ----------------
// Pass 1: per (b, chunk, d) compute local suffix S[n] and chunk decay P[n].
// PS layout: [b][ch][d][32]  (S in 0..15, P in 16..31)
// grid: 512 blocks (b*256 + ch*8 + dg), 256 threads (= d within group of 256)
__global__ __launch_bounds__(256) void scan_part1(const float* __restrict__ dt,
    const float* __restrict__ xs, const float* __restrict__ xdbl,
    const float* __restrict__ Alog, float* __restrict__ PS) {
  int tid = threadIdx.x;
  int dg = blockIdx.x & 7;
  int ch = (blockIdx.x >> 3) & (NCH - 1);
  int b  = blockIdx.x >> 8;
  int d  = dg * 256 + tid;
  float Ar[16];
#pragma unroll
  for (int q = 0; q < 4; ++q) {
    float4 a = *(const float4*)&Alog[d * 16 + q * 4];
    Ar[q*4+0] = -__expf(a.x); Ar[q*4+1] = -__expf(a.y);
    Ar[q*4+2] = -__expf(a.z); Ar[q*4+3] = -__expf(a.w);
  }
  __shared__ float Bs[CLEN][16];
  for (int i = tid; i < CLEN * 16; i += 256) {
    int t = i >> 4, n = i & 15;
    int m = b * 1024 + ch * CLEN + t;
    Bs[t][n] = xdbl[m * 128 + 64 + n];
  }
  __syncthreads();
  float S[16];
#pragma unroll
  for (int n = 0; n < 16; ++n) S[n] = 0.f;
  float sumdt = 0.f;
  int mbase = b * 1024 + ch * CLEN;
  for (int t = 0; t < CLEN; ++t) {
    float dtv = dt[(size_t)(mbase + t) * 2048 + d];
    float xv  = xs[(size_t)(mbase + t) * 2048 + d];
    sumdt += dtv;
    float dx = dtv * xv;
    float4 B0 = *(const float4*)&Bs[t][0];
    float4 B1 = *(const float4*)&Bs[t][4];
    float4 B2 = *(const float4*)&Bs[t][8];
    float4 B3 = *(const float4*)&Bs[t][12];
    const float* Bp[4] = {(const float*)&B0, (const float*)&B1, (const float*)&B2, (const float*)&B3};
#pragma unroll
    for (int n = 0; n < 16; ++n)
      S[n] = __expf(dtv * Ar[n]) * S[n] + dx * Bp[n >> 2][n & 3];
  }
  float* p = PS + ((size_t)(b * NCH + ch) * 2048 + d) * 32;
#pragma unroll
  for (int n = 0; n < 16; ++n) p[n] = S[n];
#pragma unroll
  for (int n = 0; n < 16; ++n) p[16 + n] = __expf(Ar[n] * sumdt);
}

// Pass 2: rebuild h_start from predecessor summaries, replay chunk, emit gated y (bf16).
__global__ __launch_bounds__(256) void scan_part2(const float* __restrict__ dt,
    const float* __restrict__ xs, const float* __restrict__ xdbl,
    const float* __restrict__ Alog, const float* __restrict__ Dv,
    const float* __restrict__ xz, const float* __restrict__ PS,
    u16* __restrict__ yg) {
  int tid = threadIdx.x;
  int dg = blockIdx.x & 7;
  int ch = (blockIdx.x >> 3) & (NCH - 1);
  int b  = blockIdx.x >> 8;
  int d  = dg * 256 + tid;
  float Ar[16];
#pragma unroll
  for (int q = 0; q < 4; ++q) {
    float4 a = *(const float4*)&Alog[d * 16 + q * 4];
    Ar[q*4+0] = -__expf(a.x); Ar[q*4+1] = -__expf(a.y);
    Ar[q*4+2] = -__expf(a.z); Ar[q*4+3] = -__expf(a.w);
  }
  float Dvd = Dv[d];
  // prologue: h_start = sum_j ( prod_{i>j} P_i ) * S_j   for j < ch
  float h[16], pp[16];
#pragma unroll
  for (int n = 0; n < 16; ++n) { h[n] = 0.f; pp[n] = 1.f; }
  for (int j = ch - 1; j >= 0; --j) {
    const float* q = PS + ((size_t)(b * NCH + j) * 2048 + d) * 32;
#pragma unroll
    for (int n = 0; n < 16; ++n) h[n] += pp[n] * q[n];
#pragma unroll
    for (int n = 0; n < 16; ++n) pp[n] *= q[16 + n];
  }
  __shared__ float BCs[CLEN][32];
  for (int i = tid; i < CLEN * 32; i += 256) {
    int t = i >> 5, n = i & 31;
    int m = b * 1024 + ch * CLEN + t;
    BCs[t][n] = xdbl[m * 128 + 64 + n];
  }
  __syncthreads();
  int mbase = b * 1024 + ch * CLEN;
  for (int t = 0; t < CLEN; ++t) {
    size_t mrow = (size_t)(mbase + t);
    float dtv = dt[mrow * 2048 + d];
    float xv  = xs[mrow * 2048 + d];
    float zv  = xz[mrow * 4096 + 2048 + d];
    float dx = dtv * xv;
    float4 B0 = *(const float4*)&BCs[t][0];
    float4 B1 = *(const float4*)&BCs[t][4];
    float4 B2 = *(const float4*)&BCs[t][8];
    float4 B3 = *(const float4*)&BCs[t][12];
    float4 C0 = *(const float4*)&BCs[t][16];
    float4 C1 = *(const float4*)&BCs[t][20];
    float4 C2 = *(const float4*)&BCs[t][24];
    float4 C3 = *(const float4*)&BCs[t][28];
    const float* Bp[4] = {(const float*)&B0, (const float*)&B1, (const float*)&B2, (const float*)&B3};
    const float* Cp[4] = {(const float*)&C0, (const float*)&C1, (const float*)&C2, (const float*)&C3};
#pragma unroll
    for (int n = 0; n < 16; ++n)
      h[n] = __expf(dtv * Ar[n]) * h[n] + dx * Bp[n >> 2][n & 3];
    float y0 = 0.f, y1 = 0.f, y2 = 0.f, y3 = 0.f;
#pragma unroll
    for (int n = 0; n < 4; ++n) {
      y0 += h[n]      * Cp[0][n];
      y1 += h[4 + n]  * Cp[1][n];
      y2 += h[8 + n]  * Cp[2][n];
      y3 += h[12 + n] * Cp[3][n];
    }
    float y = (y0 + y1) + (y2 + y3) + xv * Dvd;
    float sz = zv / (1.f + __expf(-zv));
    yg[mrow * 2048 + d] = f2bf(y * sz);
  }
}

// ---------------- head ----------------
__global__ __launch_bounds__(256) void final_ln_last_k(const float* __restrict__ xb,
    const float* __restrict__ w, const float* __restrict__ b, float* __restrict__ out) {
  int bb = blockIdx.x, tid = threadIdx.x;
  const float* x = xb + (size_t)(bb * 1024 + 1023) * 1024;
  float4 v = ((const float4*)x)[tid];
  float s = v.x + v.y + v.z + v.w;
  float q = v.x*v.x + v.y*v.y + v.z*v.z + v.w*v.w;
  for (int o = 32; o; o >>= 1) { s += __shfl_down(s, o); q += __shfl_down(q, o); }
  __shared__ float sb[4], qb[4];
  int wv = tid >> 6, lane = tid & 63;
  if (lane == 0) { sb[wv] = s; qb[wv] = q; }
  __syncthreads();
  s = sb[0] + sb[1] + sb[2] + sb[3];
  q = qb[0] + qb[1] + qb[2] + qb[3];
  float mean = s * (1.f / 1024.f);
  float rstd = rsqrtf(q * (1.f / 1024.f) - mean * mean + 1e-5f);
  float4 wv4 = ((const float4*)w)[tid];
  float4 bv4 = ((const float4*)b)[tid];
  float4 o;
  o.x = (v.x - mean) * rstd * wv4.x + bv4.x;
  o.y = (v.y - mean) * rstd * wv4.y + bv4.y;
  o.z = (v.z - mean) * rstd * wv4.z + bv4.z;
  o.w = (v.w - mean) * rstd * wv4.w + bv4.w;
  ((float4*)(out + bb * 1024))[tid] = o;
}

__global__ __launch_bounds__(256) void gemv_head1_k(const float* __restrict__ X,
    const float* __restrict__ W, const float* __restrict__ bias, float* __restrict__ out) {
  int gw = (blockIdx.x * 256 + threadIdx.x) >> 6;  // 0..4095
  int lane = threadIdx.x & 63;
  int b = gw >> 11, j = gw & 2047;
  const float* x = X + b * 1024;
  const float* w = W + (size_t)j * 1024;
  float s = 0.f;
#pragma unroll
  for (int q = 0; q < 4; ++q) {
    int col = q * 256 + lane * 4;
    float4 xv = *(const float4*)&x[col];
    float4 wv = *(const float4*)&w[col];
    s += xv.x*wv.x + xv.y*wv.y + xv.z*wv.z + xv.w*wv.w;
  }
  for (int o = 32; o; o >>= 1) s += __shfl_down(s, o);
  if (lane == 0) out[gw] = s + bias[j];
}

__global__ __launch_bounds__(256) void ln_gelu_k(const float* __restrict__ X,
    const float* __restrict__ w, const float* __restrict__ b, float* __restrict__ out) {
  int row = blockIdx.x, tid = threadIdx.x;
  const float* x = X + (size_t)row * 2048;
  float4 v0 = ((const float4*)x)[tid];
  float4 v1 = ((const float4*)x)[tid + 256];
  float s = v0.x+v0.y+v0.z+v0.w + v1.x+v1.y+v1.z+v1.w;
  float q = v0.x*v0.x+v0.y*v0.y+v0.z*v0.z+v0.w*v0.w
          + v1.x*v1.x+v1.y*v1.y+v1.z*v1.z+v1.w*v1.w;
  for (int o = 32; o; o >>= 1) { s += __shfl_down(s, o); q += __shfl_down(q, o); }
  __shared__ float sb[4], qb[4];
  int wv = tid >> 6, lane = tid & 63;
  if (lane == 0) { sb[wv] = s; qb[wv] = q; }
  __syncthreads();
  s = sb[0] + sb[1] + sb[2] + sb[3];
  q = qb[0] + qb[1] + qb[2] + qb[3];
  float mean = s * (1.f / 2048.f);
  float rstd = rsqrtf(q * (1.f / 2048.f) - mean * mean + 1e-5f);
  float* o0 = out + (size_t)row * 2048;
#pragma unroll
  for (int h = 0; h < 2; ++h) {
    float4 v = h ? v1 : v0;
    int c0 = tid * 4 + h * 1024;
    float4 wv4 = *(const float4*)&w[c0];
    float4 bv4 = *(const float4*)&b[c0];
    float4 g;
    g.x = (v.x - mean) * rstd * wv4.x + bv4.x;
    g.y = (v.y - mean) * rstd * wv4.y + bv4.y;
    g.z = (v.z - mean) * rstd * wv4.z + bv4.z;
    g.w = (v.w - mean) * rstd * wv4.w + bv4.w;
    g.x = 0.5f * g.x * (1.f + erff(g.x * 0.70710678f));
    g.y = 0.5f * g.y * (1.f + erff(g.y * 0.70710678f));
    g.z = 0.5f * g.z * (1.f + erff(g.z * 0.70710678f));
    g.w = 0.5f * g.w * (1.f + erff(g.w * 0.70710678f));
    *(float4*)&o0[c0] = g;
  }
}

__global__ __launch_bounds__(256) void gemv_head2_k(const float* __restrict__ X,
    const float* __restrict__ W, const float* __restrict__ bias, float* __restrict__ out) {
  int gw = (blockIdx.x * 256 + threadIdx.x) >> 6;  // 0..1999
  int lane = threadIdx.x & 63;
  int b = (gw >= 1000) ? 1 : 0;
  int j = gw - b * 1000;
  const float* x = X + b * 2048;
  const float* w = W + (size_t)j * 2048;
  float s = 0.f;
#pragma unroll
  for (int q = 0; q < 8; ++q) {
    int col = q * 256 + lane * 4;
    float4 xv = *(const float4*)&x[col];
    float4 wv = *(const float4*)&w[col];
    s += xv.x*wv.x + xv.y*wv.y + xv.z*wv.z + xv.w*wv.w;
  }
  for (int o = 32; o; o >>= 1) s += __shfl_down(s, o);
  if (lane == 0) out[gw] = s + bias[j];
}

// ---------------- launch ----------------
extern "C" void kernel_launch(void* const* d_in, const int* in_sizes, int n_in,
                              void* d_out, int out_size, void* d_ws, size_t ws_size,
                              hipStream_t stream) {
  const float* x_in = (const float*)d_in[0];
  const float* lnw  = (const float*)d_in[1];
  const float* lnb  = (const float*)d_in[2];
  const float* ipw  = (const float*)d_in[3];
  const float* cw   = (const float*)d_in[4];
  const float* cb   = (const float*)d_in[5];
  const float* xpw  = (const float*)d_in[6];
  const float* dpw  = (const float*)d_in[7];
  const float* dpb  = (const float*)d_in[8];
  const float* Alog = (const float*)d_in[9];
  const float* Dv   = (const float*)d_in[10];
  const float* opw  = (const float*)d_in[11];
  const float* fnw  = (const float*)d_in[12];
  const float* fnb  = (const float*)d_in[13];
  const float* h1w  = (const float*)d_in[14];
  const float* h1b  = (const float*)d_in[15];
  const float* hlnw = (const float*)d_in[16];
  const float* hlnb = (const float*)d_in[17];
  const float* h2w  = (const float*)d_in[18];
  const float* h2b  = (const float*)d_in[19];
  float* out = (float*)d_out;

  char* ws = (char*)d_ws;
  size_t off = 0;
  auto alloc = [&](size_t bytes) -> void* {
    void* p = ws + off; off += (bytes + 255) & ~(size_t)255; return p;
  };
  float* x_buf    = (float*)alloc((size_t)MTOK * DMODEL * 4);
  u16*   xn_bf    = (u16*)  alloc((size_t)MTOK * DMODEL * 2);
  float* xz       = (float*)alloc((size_t)MTOK * 2 * DINNER * 4);
  float* xs       = (float*)alloc((size_t)MTOK * DINNER * 4);
  u16*   xs_bf    = (u16*)  alloc((size_t)MTOK * DINNER * 2);
  float* xdbl     = (float*)alloc((size_t)MTOK * 128 * 4);
  u16*   dtin_bf  = (u16*)  alloc((size_t)MTOK * DTRANK * 2);
  float* dtbuf    = (float*)alloc((size_t)MTOK * DINNER * 4);
  u16*   yg_bf    = (u16*)  alloc((size_t)MTOK * DINNER * 2);
  u16*   w_ip     = (u16*)  alloc((size_t)2 * DINNER * DMODEL * 2);
  u16*   w_xp     = (u16*)  alloc((size_t)128 * DINNER * 2);
  u16*   w_dt     = (u16*)  alloc((size_t)DINNER * DTRANK * 2);
  u16*   w_op     = (u16*)  alloc((size_t)DMODEL * DINNER * 2);
  float* PS       = (float*)alloc((size_t)NBATCH * NCH * DINNER * 32 * 4);
  float* lastn    = (float*)alloc(2 * 1024 * 4);
  float* hpre     = (float*)alloc(2 * 2048 * 4);
  float* hbuf     = (float*)alloc(2 * 2048 * 4);

  hipMemcpyAsync(x_buf, x_in, (size_t)MTOK * DMODEL * 4, hipMemcpyDeviceToDevice, stream);

  for (int i = 0; i < NLAYER; ++i) {
    f32_to_bf16_k<<<4096, 256, 0, stream>>>(ipw + (size_t)i * 2 * DINNER * DMODEL, w_ip, 2 * DINNER * DMODEL);
    cvt_pad_xproj_k<<<256, 256, 0, stream>>>(xpw + (size_t)i * 96 * DINNER, w_xp);
    f32_to_bf16_k<<<128, 256, 0, stream>>>(dpw + (size_t)i * DINNER * DTRANK, w_dt, DINNER * DTRANK);
    f32_to_bf16_k<<<2048, 256, 0, stream>>>(opw + (size_t)i * DMODEL * DINNER, w_op, DMODEL * DINNER);
    ln_to_bf16_k<<<MTOK, 256, 0, stream>>>(x_buf, lnw + i * DMODEL, lnb + i * DMODEL, xn_bf);
    { dim3 g(16, 32, 1);
      gemm_bt<0><<<g, 256, 0, stream>>>(xn_bf, w_ip, xz, nullptr, 1024, 1024, 4096, 1024); }
    conv_silu_k<<<4096, 256, 0, stream>>>(xz, cw + (size_t)i * DINNER * 4, cb + i * DINNER, xs, xs_bf);
    hipMemsetAsync(xdbl, 0, (size_t)MTOK * 128 * 4, stream);
    { dim3 g(16, 1, 8);
      gemm_bt<3><<<g, 256, 0, stream>>>(xs_bf, w_xp, xdbl, nullptr, 2048, 2048, 128, 256); }
    cvt_dtin_k<<<128, 256, 0, stream>>>(xdbl, dtin_bf);
    { dim3 g(16, 16, 1);
      gemm_bt<2><<<g, 256, 0, stream>>>(dtin_bf, w_dt, dtbuf, dpb + i * DINNER, 64, 64, 2048, 64); }
    scan_part1<<<512, 256, 0, stream>>>(dtbuf, xs, xdbl, Alog + (size_t)i * DINNER * DSTATE, PS);
    scan_part2<<<512, 256, 0, stream>>>(dtbuf, xs, xdbl, Alog + (size_t)i * DINNER * DSTATE,
                                        Dv + i * DINNER, xz, PS, yg_bf);
    { dim3 g(16, 8, 2);
      gemm_bt<3><<<g, 256, 0, stream>>>(yg_bf, w_op, x_buf, nullptr, 2048, 2048, 1024, 1024); }
  }
  final_ln_last_k<<<2, 256, 0, stream>>>(x_buf, fnw, fnb, lastn);
  gemv_head1_k<<<1024, 256, 0, stream>>>(lastn, h1w, h1b, hpre);
  ln_gelu_k<<<2, 256, 0, stream>>>(hpre, hlnw, hlnb, hbuf);
  gemv_head2_k<<<500, 256, 0, stream>>>(hbuf, h2w, h2b, out);
  (void)in_sizes; (void)n_in; (void)out_size; (void)ws_size;
}

// Round 3
// 799.974 us; speedup vs baseline: 1.8819x; 1.2926x over previous
//
#include <hip/hip_runtime.h>

typedef unsigned short u16;
using short8 = __attribute__((ext_vector_type(8))) short;
using f32x4  = __attribute__((ext_vector_type(4))) float;

#define NLAYER 4
#define DMODEL 1024
#define DSTATE 16
#define DINNER 2048
#define DTRANK 64
#define SEQL   1024
#define NBATCH 2
#define MTOK   2048   /* NBATCH*SEQL */
#define NCH    64     /* scan chunks per sequence */
#define CLEN   16     /* timesteps per chunk: NCH*CLEN == SEQL */

__device__ __forceinline__ u16 f2bf(float f) {
  union { float f; unsigned int u; } cv; cv.f = f;
  return (u16)((cv.u + 0x7FFFu + ((cv.u >> 16) & 1u)) >> 16);
}
__device__ __forceinline__ float bf2f(u16 v) {
  union { unsigned int u; float f; } cv; cv.u = ((unsigned int)v) << 16; return cv.f;
}

// ---------------- weight conversion ----------------
__global__ __launch_bounds__(256) void f32_to_bf16_k(const float* __restrict__ src,
                                                     u16* __restrict__ dst, int n) {
  int i4 = (blockIdx.x * 256 + threadIdx.x) * 4;
  if (i4 >= n) return;
  float4 v = *(const float4*)&src[i4];
  ushort4 o; o.x = f2bf(v.x); o.y = f2bf(v.y); o.z = f2bf(v.z); o.w = f2bf(v.w);
  *(ushort4*)&dst[i4] = o;
}

// x_proj_w (96 x 2048) -> padded (128 x 2048) bf16
__global__ __launch_bounds__(256) void cvt_pad_xproj_k(const float* __restrict__ src,
                                                       u16* __restrict__ dst) {
  int i4 = (blockIdx.x * 256 + threadIdx.x) * 4;   // total 128*2048
  int row = i4 >> 11, col = i4 & 2047;
  float4 v = make_float4(0.f, 0.f, 0.f, 0.f);
  if (row < 96) v = *(const float4*)&src[row * 2048 + col];
  ushort4 o; o.x = f2bf(v.x); o.y = f2bf(v.y); o.z = f2bf(v.z); o.w = f2bf(v.w);
  *(ushort4*)&dst[i4] = o;
}

// xdbl (2048 x 128) cols 0..63 -> bf16 (2048 x 64)
__global__ __launch_bounds__(256) void cvt_dtin_k(const float* __restrict__ xdbl,
                                                  u16* __restrict__ dtin) {
  int i4 = (blockIdx.x * 256 + threadIdx.x) * 4;   // total 2048*64
  int m = i4 >> 6, r = i4 & 63;
  float4 v = *(const float4*)&xdbl[m * 128 + r];
  ushort4 o; o.x = f2bf(v.x); o.y = f2bf(v.y); o.z = f2bf(v.z); o.w = f2bf(v.w);
  *(ushort4*)&dtin[i4] = o;
}

// ---------------- LayerNorm -> bf16 (row = 1024) ----------------
__global__ __launch_bounds__(256) void ln_to_bf16_k(const float* __restrict__ X,
    const float* __restrict__ w, const float* __restrict__ b, u16* __restrict__ out) {
  int row = blockIdx.x, tid = threadIdx.x;
  const float* x = X + (size_t)row * 1024;
  float4 v = ((const float4*)x)[tid];
  float s = v.x + v.y + v.z + v.w;
  float q = v.x*v.x + v.y*v.y + v.z*v.z + v.w*v.w;
  for (int o = 32; o; o >>= 1) { s += __shfl_down(s, o); q += __shfl_down(q, o); }
  __shared__ float sb[4], qb[4];
  int wv = tid >> 6, lane = tid & 63;
  if (lane == 0) { sb[wv] = s; qb[wv] = q; }
  __syncthreads();
  s = sb[0] + sb[1] + sb[2] + sb[3];
  q = qb[0] + qb[1] + qb[2] + qb[3];
  float mean = s * (1.f / 1024.f);
  float var  = q * (1.f / 1024.f) - mean * mean;
  float rstd = rsqrtf(var + 1e-5f);
  float4 wv4 = ((const float4*)w)[tid];
  float4 bv4 = ((const float4*)b)[tid];
  ushort4 o4;
  o4.x = f2bf((v.x - mean) * rstd * wv4.x + bv4.x);
  o4.y = f2bf((v.y - mean) * rstd * wv4.y + bv4.y);
  o4.z = f2bf((v.z - mean) * rstd * wv4.z + bv4.z);
  o4.w = f2bf((v.w - mean) * rstd * wv4.w + bv4.w);
  ((ushort4*)(out + (size_t)row * 1024))[tid] = o4;
}

// ---------------- MFMA GEMM: C[M,N] = A[M,K] * W[N,K]^T ----------------
__device__ __forceinline__ void stage_tile(const u16* G, int ld, int row0, int k0,
                                           u16* S, int tid) {
  int w = tid >> 6;
#pragma unroll
  for (int j = 0; j < 2; ++j) {
    int t = tid + j * 256;
    int r = t >> 2;
    int c = (t & 3) << 3;
    const u16* g = G + (size_t)(row0 + r) * ld + (k0 + c);
    u16* s = S + w * 512 + j * 2048;  // wave-uniform base; HW adds lane*16B
    __builtin_amdgcn_global_load_lds((const __attribute__((address_space(1))) void*)g,
                                     (__attribute__((address_space(3))) void*)s,
                                     16, 0, 0);
  }
}

// EPI: 0 = f32 store, 1 = bf16 store, 2 = softplus(bias add) f32, 3 = atomicAdd f32
template<int EPI>
__global__ __launch_bounds__(256) void gemm_bt(const u16* __restrict__ A,
    const u16* __restrict__ Bw, float* __restrict__ C, const float* __restrict__ bias,
    int lda, int ldb, int ldc, int kchunk) {
  __shared__ u16 As[128 * 32];
  __shared__ u16 Bs[128 * 32];
  int tid = threadIdx.x;
  int bm = blockIdx.x, bn = blockIdx.y;
  int kb = blockIdx.z * kchunk, ke = kb + kchunk;
  int lane = tid & 63, w = tid >> 6;
  int wr = (w >> 1) * 64, wc = (w & 1) * 64;
  int fr = lane & 15;
  int kg = (lane >> 4) * 8;
  f32x4 acc[4][4] = {};
  for (int k0 = kb; k0 < ke; k0 += 32) {
    __syncthreads();
    stage_tile(A, lda, bm * 128, k0, As, tid);
    stage_tile(Bw, ldb, bn * 128, k0, Bs, tid);
    __syncthreads();
    short8 a[4], b[4];
#pragma unroll
    for (int mf = 0; mf < 4; ++mf)
      a[mf] = *(const short8*)&As[(wr + mf * 16 + fr) * 32 + kg];
#pragma unroll
    for (int nf = 0; nf < 4; ++nf)
      b[nf] = *(const short8*)&Bs[(wc + nf * 16 + fr) * 32 + kg];
#pragma unroll
    for (int mf = 0; mf < 4; ++mf)
#pragma unroll
      for (int nf = 0; nf < 4; ++nf)
        acc[mf][nf] = __builtin_amdgcn_mfma_f32_16x16x32_bf16(a[mf], b[nf], acc[mf][nf], 0, 0, 0);
  }
  int r0 = bm * 128 + wr + (lane >> 4) * 4;
  int c0 = bn * 128 + wc + (lane & 15);
#pragma unroll
  for (int mf = 0; mf < 4; ++mf) {
#pragma unroll
    for (int nf = 0; nf < 4; ++nf) {
#pragma unroll
      for (int r = 0; r < 4; ++r) {
        int gr = r0 + mf * 16 + r;
        int gc = c0 + nf * 16;
        float v = acc[mf][nf][r];
        size_t idx = (size_t)gr * ldc + gc;
        if (EPI == 0) {
          C[idx] = v;
        } else if (EPI == 1) {
          ((u16*)C)[idx] = f2bf(v);
        } else if (EPI == 2) {
          v += bias[gc];
          v = (v > 20.f) ? v : log1pf(__expf(v));
          C[idx] = v;
        } else {
          atomicAdd(&C[idx], v);
        }
      }
    }
  }
}

// ---------------- causal depthwise conv (K=4) + SiLU, bf16 in/out ----------------
__global__ __launch_bounds__(256) void conv_silu_k(const u16* __restrict__ xzb,
    const float* __restrict__ cw, const float* __restrict__ cb,
    u16* __restrict__ xsb) {
  int idx = blockIdx.x * 256 + threadIdx.x;  // 2048 * 512
  int m = idx >> 9;
  int d = (idx & 511) << 2;
  int t = m & (SEQL - 1);
  float4 w0 = *(const float4*)&cw[(d + 0) * 4];
  float4 w1 = *(const float4*)&cw[(d + 1) * 4];
  float4 w2 = *(const float4*)&cw[(d + 2) * 4];
  float4 w3 = *(const float4*)&cw[(d + 3) * 4];
  float4 acc = *(const float4*)&cb[d];
#pragma unroll
  for (int j = 0; j < 4; ++j) {
    int tt = t - 3 + j;
    if (tt >= 0) {
      ushort4 xv = *(const ushort4*)&xzb[(size_t)(m - 3 + j) * 4096 + d];
      acc.x += bf2f(xv.x) * ((const float*)&w0)[j];
      acc.y += bf2f(xv.y) * ((const float*)&w1)[j];
      acc.z += bf2f(xv.z) * ((const float*)&w2)[j];
      acc.w += bf2f(xv.w) * ((const float*)&w3)[j];
    }
  }
  float4 o;
  o.x = acc.x / (1.f + __expf(-acc.x));
  o.y = acc.y / (1.f + __expf(-acc.y));
  o.z = acc.z / (1.f + __expf(-acc.z));
  o.w = acc.w / (1.f + __expf(-acc.w));
  ushort4 ob; ob.x = f2bf(o.x); ob.y = f2bf(o.y); ob.z = f2bf(o.z); ob.w = f2bf(o.w);
  *(ushort4*)&xsb[(size_t)m * 2048 + d] = ob;
}

// ---------------- chunked selective scan ----------------
// PS layout: [b][ch][d][32]  (S in 0..15, P in 16..31)
// Hstart:    [b][ch][d][16]
// grid part1/part2: 1024 blocks (b*512 + ch*8 + dg), 256 threads (d = dg*256+tid)

__global__ __launch_bounds__(256) void scan_part1(const float* __restrict__ dt,
    const u16* __restrict__ xsb, const float* __restrict__ xdbl,
    const float* __restrict__ Alog, float* __restrict__ PS) {
  int tid = threadIdx.x;
  int dg = blockIdx.x & 7;
  int ch = (blockIdx.x >> 3) & (NCH - 1);
  int b  = blockIdx.x >> 9;
  int d  = dg * 256 + tid;
  float Ar[16];
#pragma unroll
  for (int q = 0; q < 4; ++q) {
    float4 a = *(const float4*)&Alog[d * 16 + q * 4];
    Ar[q*4+0] = -__expf(a.x); Ar[q*4+1] = -__expf(a.y);
    Ar[q*4+2] = -__expf(a.z); Ar[q*4+3] = -__expf(a.w);
  }
  __shared__ float Bs[CLEN][16];
  if (tid < CLEN * 16) {
    int t = tid >> 4, n = tid & 15;
    int m = b * SEQL + ch * CLEN + t;
    Bs[t][n] = xdbl[m * 128 + 64 + n];
  }
  __syncthreads();
  int mbase = b * SEQL + ch * CLEN;
  float dtv[CLEN], xv[CLEN];
#pragma unroll
  for (int t = 0; t < CLEN; ++t) dtv[t] = dt[(size_t)(mbase + t) * 2048 + d];
#pragma unroll
  for (int t = 0; t < CLEN; ++t) xv[t] = bf2f(xsb[(size_t)(mbase + t) * 2048 + d]);
  float S[16];
#pragma unroll
  for (int n = 0; n < 16; ++n) S[n] = 0.f;
  float sumdt = 0.f;
  for (int t = 0; t < CLEN; ++t) {
    sumdt += dtv[t];
    float dx = dtv[t] * xv[t];
    float4 B0 = *(const float4*)&Bs[t][0];
    float4 B1 = *(const float4*)&Bs[t][4];
    float4 B2 = *(const float4*)&Bs[t][8];
    float4 B3 = *(const float4*)&Bs[t][12];
    const float* Bp[4] = {(const float*)&B0, (const float*)&B1, (const float*)&B2, (const float*)&B3};
#pragma unroll
    for (int n = 0; n < 16; ++n)
      S[n] = __expf(dtv[t] * Ar[n]) * S[n] + dx * Bp[n >> 2][n & 3];
  }
  float* p = PS + ((size_t)(b * NCH + ch) * 2048 + d) * 32;
#pragma unroll
  for (int n = 0; n < 16; ++n) p[n] = S[n];
#pragma unroll
  for (int n = 0; n < 16; ++n) p[16 + n] = __expf(Ar[n] * sumdt);
}

// prefix combine across chunks: one thread per (b,d,n)
__global__ __launch_bounds__(256) void scan_prefix(const float* __restrict__ PS,
                                                   float* __restrict__ Hstart) {
  int id = blockIdx.x * 256 + threadIdx.x;   // 2*2048*16 = 65536
  int n = id & 15;
  int d = (id >> 4) & 2047;
  int b = id >> 15;
  size_t sbase = ((size_t)b * NCH) * 2048 * 32 + (size_t)d * 32 + n;
  size_t hbase = ((size_t)b * NCH) * 2048 * 16 + (size_t)d * 16 + n;
  float h = 0.f;
#pragma unroll 8
  for (int ch = 0; ch < NCH; ++ch) {
    Hstart[hbase + (size_t)ch * (2048 * 16)] = h;
    float S = PS[sbase + (size_t)ch * (2048 * 32)];
    float P = PS[sbase + (size_t)ch * (2048 * 32) + 16];
    h = fmaf(P, h, S);
  }
}

__global__ __launch_bounds__(256) void scan_part2(const float* __restrict__ dt,
    const u16* __restrict__ xsb, const float* __restrict__ xdbl,
    const float* __restrict__ Alog, const float* __restrict__ Dv,
    const u16* __restrict__ xzb, const float* __restrict__ Hstart,
    u16* __restrict__ yg) {
  int tid = threadIdx.x;
  int dg = blockIdx.x & 7;
  int ch = (blockIdx.x >> 3) & (NCH - 1);
  int b  = blockIdx.x >> 9;
  int d  = dg * 256 + tid;
  float Ar[16];
#pragma unroll
  for (int q = 0; q < 4; ++q) {
    float4 a = *(const float4*)&Alog[d * 16 + q * 4];
    Ar[q*4+0] = -__expf(a.x); Ar[q*4+1] = -__expf(a.y);
    Ar[q*4+2] = -__expf(a.z); Ar[q*4+3] = -__expf(a.w);
  }
  float Dvd = Dv[d];
  __shared__ float BCs[CLEN][32];
  if (tid < 256) {
    int t = tid >> 5, n = tid & 31;
    int m = b * SEQL + ch * CLEN + t;
    BCs[t][n] = xdbl[m * 128 + 64 + n];
    int t2 = t + 8;
    int m2 = m + 8;
    BCs[t2][n] = xdbl[m2 * 128 + 64 + n];
  }
  // load h_start (16 consecutive floats)
  const float* hs = Hstart + ((size_t)(b * NCH + ch) * 2048 + d) * 16;
  float h[16];
#pragma unroll
  for (int q = 0; q < 4; ++q) {
    float4 hv = *(const float4*)&hs[q * 4];
    h[q*4+0] = hv.x; h[q*4+1] = hv.y; h[q*4+2] = hv.z; h[q*4+3] = hv.w;
  }
  int mbase = b * SEQL + ch * CLEN;
  float dtv[CLEN], xv[CLEN], zv[CLEN];
#pragma unroll
  for (int t = 0; t < CLEN; ++t) dtv[t] = dt[(size_t)(mbase + t) * 2048 + d];
#pragma unroll
  for (int t = 0; t < CLEN; ++t) xv[t] = bf2f(xsb[(size_t)(mbase + t) * 2048 + d]);
#pragma unroll
  for (int t = 0; t < CLEN; ++t) zv[t] = bf2f(xzb[(size_t)(mbase + t) * 4096 + 2048 + d]);
  __syncthreads();
  for (int t = 0; t < CLEN; ++t) {
    float dx = dtv[t] * xv[t];
    float4 B0 = *(const float4*)&BCs[t][0];
    float4 B1 = *(const float4*)&BCs[t][4];
    float4 B2 = *(const float4*)&BCs[t][8];
    float4 B3 = *(const float4*)&BCs[t][12];
    float4 C0 = *(const float4*)&BCs[t][16];
    float4 C1 = *(const float4*)&BCs[t][20];
    float4 C2 = *(const float4*)&BCs[t][24];
    float4 C3 = *(const float4*)&BCs[t][28];
    const float* Bp[4] = {(const float*)&B0, (const float*)&B1, (const float*)&B2, (const float*)&B3};
    const float* Cp[4] = {(const float*)&C0, (const float*)&C1, (const float*)&C2, (const float*)&C3};
#pragma unroll
    for (int n = 0; n < 16; ++n)
      h[n] = __expf(dtv[t] * Ar[n]) * h[n] + dx * Bp[n >> 2][n & 3];
    float y0 = 0.f, y1 = 0.f, y2 = 0.f, y3 = 0.f;
#pragma unroll
    for (int n = 0; n < 4; ++n) {
      y0 += h[n]      * Cp[0][n];
      y1 += h[4 + n]  * Cp[1][n];
      y2 += h[8 + n]  * Cp[2][n];
      y3 += h[12 + n] * Cp[3][n];
    }
    float y = (y0 + y1) + (y2 + y3) + xv[t] * Dvd;
    float sz = zv[t] / (1.f + __expf(-zv[t]));
    yg[(size_t)(mbase + t) * 2048 + d] = f2bf(y * sz);
  }
}

// ---------------- head ----------------
__global__ __launch_bounds__(256) void final_ln_last_k(const float* __restrict__ xb,
    const float* __restrict__ w, const float* __restrict__ b, float* __restrict__ out) {
  int bb = blockIdx.x, tid = threadIdx.x;
  const float* x = xb + (size_t)(bb * 1024 + 1023) * 1024;
  float4 v = ((const float4*)x)[tid];
  float s = v.x + v.y + v.z + v.w;
  float q = v.x*v.x + v.y*v.y + v.z*v.z + v.w*v.w;
  for (int o = 32; o; o >>= 1) { s += __shfl_down(s, o); q += __shfl_down(q, o); }
  __shared__ float sb[4], qb[4];
  int wv = tid >> 6, lane = tid & 63;
  if (lane == 0) { sb[wv] = s; qb[wv] = q; }
  __syncthreads();
  s = sb[0] + sb[1] + sb[2] + sb[3];
  q = qb[0] + qb[1] + qb[2] + qb[3];
  float mean = s * (1.f / 1024.f);
  float rstd = rsqrtf(q * (1.f / 1024.f) - mean * mean + 1e-5f);
  float4 wv4 = ((const float4*)w)[tid];
  float4 bv4 = ((const float4*)b)[tid];
  float4 o;
  o.x = (v.x - mean) * rstd * wv4.x + bv4.x;
  o.y = (v.y - mean) * rstd * wv4.y + bv4.y;
  o.z = (v.z - mean) * rstd * wv4.z + bv4.z;
  o.w = (v.w - mean) * rstd * wv4.w + bv4.w;
  ((float4*)(out + bb * 1024))[tid] = o;
}

__global__ __launch_bounds__(256) void gemv_head1_k(const float* __restrict__ X,
    const float* __restrict__ W, const float* __restrict__ bias, float* __restrict__ out) {
  int gw = (blockIdx.x * 256 + threadIdx.x) >> 6;  // 0..4095
  int lane = threadIdx.x & 63;
  int b = gw >> 11, j = gw & 2047;
  const float* x = X + b * 1024;
  const float* w = W + (size_t)j * 1024;
  float s = 0.f;
#pragma unroll
  for (int q = 0; q < 4; ++q) {
    int col = q * 256 + lane * 4;
    float4 xv = *(const float4*)&x[col];
    float4 wv = *(const float4*)&w[col];
    s += xv.x*wv.x + xv.y*wv.y + xv.z*wv.z + xv.w*wv.w;
  }
  for (int o = 32; o; o >>= 1) s += __shfl_down(s, o);
  if (lane == 0) out[gw] = s + bias[j];
}

__global__ __launch_bounds__(256) void ln_gelu_k(const float* __restrict__ X,
    const float* __restrict__ w, const float* __restrict__ b, float* __restrict__ out) {
  int row = blockIdx.x, tid = threadIdx.x;
  const float* x = X + (size_t)row * 2048;
  float4 v0 = ((const float4*)x)[tid];
  float4 v1 = ((const float4*)x)[tid + 256];
  float s = v0.x+v0.y+v0.z+v0.w + v1.x+v1.y+v1.z+v1.w;
  float q = v0.x*v0.x+v0.y*v0.y+v0.z*v0.z+v0.w*v0.w
          + v1.x*v1.x+v1.y*v1.y+v1.z*v1.z+v1.w*v1.w;
  for (int o = 32; o; o >>= 1) { s += __shfl_down(s, o); q += __shfl_down(q, o); }
  __shared__ float sb[4], qb[4];
  int wv = tid >> 6, lane = tid & 63;
  if (lane == 0) { sb[wv] = s; qb[wv] = q; }
  __syncthreads();
  s = sb[0] + sb[1] + sb[2] + sb[3];
  q = qb[0] + qb[1] + qb[2] + qb[3];
  float mean = s * (1.f / 2048.f);
  float rstd = rsqrtf(q * (1.f / 2048.f) - mean * mean + 1e-5f);
  float* o0 = out + (size_t)row * 2048;
#pragma unroll
  for (int h = 0; h < 2; ++h) {
    float4 v = h ? v1 : v0;
    int c0 = tid * 4 + h * 1024;
    float4 wv4 = *(const float4*)&w[c0];
    float4 bv4 = *(const float4*)&b[c0];
    float4 g;
    g.x = (v.x - mean) * rstd * wv4.x + bv4.x;
    g.y = (v.y - mean) * rstd * wv4.y + bv4.y;
    g.z = (v.z - mean) * rstd * wv4.z + bv4.z;
    g.w = (v.w - mean) * rstd * wv4.w + bv4.w;
    g.x = 0.5f * g.x * (1.f + erff(g.x * 0.70710678f));
    g.y = 0.5f * g.y * (1.f + erff(g.y * 0.70710678f));
    g.z = 0.5f * g.z * (1.f + erff(g.z * 0.70710678f));
    g.w = 0.5f * g.w * (1.f + erff(g.w * 0.70710678f));
    *(float4*)&o0[c0] = g;
  }
}

__global__ __launch_bounds__(256) void gemv_head2_k(const float* __restrict__ X,
    const float* __restrict__ W, const float* __restrict__ bias, float* __restrict__ out) {
  int gw = (blockIdx.x * 256 + threadIdx.x) >> 6;  // 0..1999
  int lane = threadIdx.x & 63;
  int b = (gw >= 1000) ? 1 : 0;
  int j = gw - b * 1000;
  const float* x = X + b * 2048;
  const float* w = W + (size_t)j * 2048;
  float s = 0.f;
#pragma unroll
  for (int q = 0; q < 8; ++q) {
    int col = q * 256 + lane * 4;
    float4 xv = *(const float4*)&x[col];
    float4 wv = *(const float4*)&w[col];
    s += xv.x*wv.x + xv.y*wv.y + xv.z*wv.z + xv.w*wv.w;
  }
  for (int o = 32; o; o >>= 1) s += __shfl_down(s, o);
  if (lane == 0) out[gw] = s + bias[j];
}

// ---------------- launch ----------------
extern "C" void kernel_launch(void* const* d_in, const int* in_sizes, int n_in,
                              void* d_out, int out_size, void* d_ws, size_t ws_size,
                              hipStream_t stream) {
  const float* x_in = (const float*)d_in[0];
  const float* lnw  = (const float*)d_in[1];
  const float* lnb  = (const float*)d_in[2];
  const float* ipw  = (const float*)d_in[3];
  const float* cw   = (const float*)d_in[4];
  const float* cb   = (const float*)d_in[5];
  const float* xpw  = (const float*)d_in[6];
  const float* dpw  = (const float*)d_in[7];
  const float* dpb  = (const float*)d_in[8];
  const float* Alog = (const float*)d_in[9];
  const float* Dv   = (const float*)d_in[10];
  const float* opw  = (const float*)d_in[11];
  const float* fnw  = (const float*)d_in[12];
  const float* fnb  = (const float*)d_in[13];
  const float* h1w  = (const float*)d_in[14];
  const float* h1b  = (const float*)d_in[15];
  const float* hlnw = (const float*)d_in[16];
  const float* hlnb = (const float*)d_in[17];
  const float* h2w  = (const float*)d_in[18];
  const float* h2b  = (const float*)d_in[19];
  float* out = (float*)d_out;

  char* ws = (char*)d_ws;
  size_t off = 0;
  auto alloc = [&](size_t bytes) -> void* {
    void* p = ws + off; off += (bytes + 255) & ~(size_t)255; return p;
  };
  float* x_buf    = (float*)alloc((size_t)MTOK * DMODEL * 4);
  u16*   xn_bf    = (u16*)  alloc((size_t)MTOK * DMODEL * 2);
  u16*   xz_bf    = (u16*)  alloc((size_t)MTOK * 2 * DINNER * 2);
  u16*   xs_bf    = (u16*)  alloc((size_t)MTOK * DINNER * 2);
  float* xdbl     = (float*)alloc((size_t)MTOK * 128 * 4);
  u16*   dtin_bf  = (u16*)  alloc((size_t)MTOK * DTRANK * 2);
  float* dtbuf    = (float*)alloc((size_t)MTOK * DINNER * 4);
  u16*   yg_bf    = (u16*)  alloc((size_t)MTOK * DINNER * 2);
  u16*   w_ip     = (u16*)  alloc((size_t)2 * DINNER * DMODEL * 2);
  u16*   w_xp     = (u16*)  alloc((size_t)128 * DINNER * 2);
  u16*   w_dt     = (u16*)  alloc((size_t)DINNER * DTRANK * 2);
  u16*   w_op     = (u16*)  alloc((size_t)DMODEL * DINNER * 2);
  float* PS       = (float*)alloc((size_t)NBATCH * NCH * DINNER * 32 * 4);
  float* Hstart   = (float*)alloc((size_t)NBATCH * NCH * DINNER * 16 * 4);
  float* lastn    = (float*)alloc(2 * 1024 * 4);
  float* hpre     = (float*)alloc(2 * 2048 * 4);
  float* hbuf     = (float*)alloc(2 * 2048 * 4);

  hipMemcpyAsync(x_buf, x_in, (size_t)MTOK * DMODEL * 4, hipMemcpyDeviceToDevice, stream);

  for (int i = 0; i < NLAYER; ++i) {
    f32_to_bf16_k<<<4096, 256, 0, stream>>>(ipw + (size_t)i * 2 * DINNER * DMODEL, w_ip, 2 * DINNER * DMODEL);
    cvt_pad_xproj_k<<<256, 256, 0, stream>>>(xpw + (size_t)i * 96 * DINNER, w_xp);
    f32_to_bf16_k<<<128, 256, 0, stream>>>(dpw + (size_t)i * DINNER * DTRANK, w_dt, DINNER * DTRANK);
    f32_to_bf16_k<<<2048, 256, 0, stream>>>(opw + (size_t)i * DMODEL * DINNER, w_op, DMODEL * DINNER);
    ln_to_bf16_k<<<MTOK, 256, 0, stream>>>(x_buf, lnw + i * DMODEL, lnb + i * DMODEL, xn_bf);
    { dim3 g(16, 32, 1);
      gemm_bt<1><<<g, 256, 0, stream>>>(xn_bf, w_ip, (float*)xz_bf, nullptr, 1024, 1024, 4096, 1024); }
    conv_silu_k<<<4096, 256, 0, stream>>>(xz_bf, cw + (size_t)i * DINNER * 4, cb + i * DINNER, xs_bf);
    hipMemsetAsync(xdbl, 0, (size_t)MTOK * 128 * 4, stream);
    { dim3 g(16, 1, 8);
      gemm_bt<3><<<g, 256, 0, stream>>>(xs_bf, w_xp, xdbl, nullptr, 2048, 2048, 128, 256); }
    cvt_dtin_k<<<128, 256, 0, stream>>>(xdbl, dtin_bf);
    { dim3 g(16, 16, 1);
      gemm_bt<2><<<g, 256, 0, stream>>>(dtin_bf, w_dt, dtbuf, dpb + i * DINNER, 64, 64, 2048, 64); }
    scan_part1<<<1024, 256, 0, stream>>>(dtbuf, xs_bf, xdbl, Alog + (size_t)i * DINNER * DSTATE, PS);
    scan_prefix<<<256, 256, 0, stream>>>(PS, Hstart);
    scan_part2<<<1024, 256, 0, stream>>>(dtbuf, xs_bf, xdbl, Alog + (size_t)i * DINNER * DSTATE,
                                         Dv + i * DINNER, xz_bf, Hstart, yg_bf);
    { dim3 g(16, 8, 2);
      gemm_bt<3><<<g, 256, 0, stream>>>(yg_bf, w_op, x_buf, nullptr, 2048, 2048, 1024, 1024); }
  }
  final_ln_last_k<<<2, 256, 0, stream>>>(x_buf, fnw, fnb, lastn);
  gemv_head1_k<<<1024, 256, 0, stream>>>(lastn, h1w, h1b, hpre);
  ln_gelu_k<<<2, 256, 0, stream>>>(hpre, hlnw, hlnb, hbuf);
  gemv_head2_k<<<500, 256, 0, stream>>>(hbuf, h2w, h2b, out);
  (void)in_sizes; (void)n_in; (void)out_size; (void)ws_size;
}

// Round 4
// 767.150 us; speedup vs baseline: 1.9624x; 1.0428x over previous
//
#include <hip/hip_runtime.h>

typedef unsigned short u16;
using short8 = __attribute__((ext_vector_type(8))) short;
using f32x4  = __attribute__((ext_vector_type(4))) float;

#define NLAYER 4
#define DMODEL 1024
#define DSTATE 16
#define DINNER 2048
#define DTRANK 64
#define SEQL   1024
#define NBATCH 2
#define MTOK   2048   /* NBATCH*SEQL */
#define NCH    64     /* scan chunks per sequence */
#define CLEN   16     /* timesteps per chunk: NCH*CLEN == SEQL */

__device__ __forceinline__ u16 f2bf(float f) {
  union { float f; unsigned int u; } cv; cv.f = f;
  return (u16)((cv.u + 0x7FFFu + ((cv.u >> 16) & 1u)) >> 16);
}
__device__ __forceinline__ float bf2f(u16 v) {
  union { unsigned int u; float f; } cv; cv.u = ((unsigned int)v) << 16; return cv.f;
}

// ---------------- batched weight conversion (all layers in one launch) ----------------
__global__ __launch_bounds__(256) void f32_to_bf16_l(const float* __restrict__ src,
                                                     u16* __restrict__ dst, int nper) {
  int l = blockIdx.y;
  int i4 = (blockIdx.x * 256 + threadIdx.x) * 4;
  if (i4 >= nper) return;
  float4 v = *(const float4*)&src[(size_t)l * nper + i4];
  ushort4 o; o.x = f2bf(v.x); o.y = f2bf(v.y); o.z = f2bf(v.z); o.w = f2bf(v.w);
  *(ushort4*)&dst[(size_t)l * nper + i4] = o;
}

// x_proj_w (L x 96 x 2048) -> padded (L x 128 x 2048) bf16
__global__ __launch_bounds__(256) void cvt_pad_xproj_l(const float* __restrict__ src,
                                                       u16* __restrict__ dst) {
  int l = blockIdx.y;
  int i4 = (blockIdx.x * 256 + threadIdx.x) * 4;   // 128*2048 per layer
  int row = i4 >> 11, col = i4 & 2047;
  float4 v = make_float4(0.f, 0.f, 0.f, 0.f);
  if (row < 96) v = *(const float4*)&src[(size_t)l * 96 * 2048 + row * 2048 + col];
  ushort4 o; o.x = f2bf(v.x); o.y = f2bf(v.y); o.z = f2bf(v.z); o.w = f2bf(v.w);
  *(ushort4*)&dst[(size_t)l * 128 * 2048 + i4] = o;
}

// ---------------- LayerNorm -> bf16 (row = 1024) ----------------
__global__ __launch_bounds__(256) void ln_to_bf16_k(const float* __restrict__ X,
    const float* __restrict__ w, const float* __restrict__ b, u16* __restrict__ out) {
  int row = blockIdx.x, tid = threadIdx.x;
  const float* x = X + (size_t)row * 1024;
  float4 v = ((const float4*)x)[tid];
  float s = v.x + v.y + v.z + v.w;
  float q = v.x*v.x + v.y*v.y + v.z*v.z + v.w*v.w;
  for (int o = 32; o; o >>= 1) { s += __shfl_down(s, o); q += __shfl_down(q, o); }
  __shared__ float sb[4], qb[4];
  int wv = tid >> 6, lane = tid & 63;
  if (lane == 0) { sb[wv] = s; qb[wv] = q; }
  __syncthreads();
  s = sb[0] + sb[1] + sb[2] + sb[3];
  q = qb[0] + qb[1] + qb[2] + qb[3];
  float mean = s * (1.f / 1024.f);
  float var  = q * (1.f / 1024.f) - mean * mean;
  float rstd = rsqrtf(var + 1e-5f);
  float4 wv4 = ((const float4*)w)[tid];
  float4 bv4 = ((const float4*)b)[tid];
  ushort4 o4;
  o4.x = f2bf((v.x - mean) * rstd * wv4.x + bv4.x);
  o4.y = f2bf((v.y - mean) * rstd * wv4.y + bv4.y);
  o4.z = f2bf((v.z - mean) * rstd * wv4.z + bv4.z);
  o4.w = f2bf((v.w - mean) * rstd * wv4.w + bv4.w);
  ((ushort4*)(out + (size_t)row * 1024))[tid] = o4;
}

// ---------------- MFMA GEMM: C[M,N] = A[M,K] * W[N,K]^T ----------------
__device__ __forceinline__ void stage_tile(const u16* G, int ld, int row0, int k0,
                                           u16* S, int tid) {
  int w = tid >> 6;
#pragma unroll
  for (int j = 0; j < 2; ++j) {
    int t = tid + j * 256;
    int r = t >> 2;
    int c = (t & 3) << 3;
    const u16* g = G + (size_t)(row0 + r) * ld + (k0 + c);
    u16* s = S + w * 512 + j * 2048;  // wave-uniform base; HW adds lane*16B
    __builtin_amdgcn_global_load_lds((const __attribute__((address_space(1))) void*)g,
                                     (__attribute__((address_space(3))) void*)s,
                                     16, 0, 0);
  }
}

// 2-phase double-buffered. EPI: 1 = bf16 store, 3 = atomicAdd f32
template<int EPI>
__global__ __launch_bounds__(256) void gemm_bt(const u16* __restrict__ A,
    const u16* __restrict__ Bw, float* __restrict__ C,
    int lda, int ldb, int ldc, int kchunk) {
  __shared__ u16 As[2][128 * 32];
  __shared__ u16 Bs[2][128 * 32];
  int tid = threadIdx.x;
  int bm = blockIdx.x, bn = blockIdx.y;
  int kb = blockIdx.z * kchunk, ke = kb + kchunk;
  int lane = tid & 63, w = tid >> 6;
  int wr = (w >> 1) * 64, wc = (w & 1) * 64;
  int fr = lane & 15;
  int kg = (lane >> 4) * 8;
  f32x4 acc[4][4] = {};
  int cur = 0;
  stage_tile(A, lda, bm * 128, kb, As[0], tid);
  stage_tile(Bw, ldb, bn * 128, kb, Bs[0], tid);
  __syncthreads();
  for (int k0 = kb; k0 < ke; k0 += 32) {
    int kn = k0 + 32;
    if (kn < ke) {
      stage_tile(A, lda, bm * 128, kn, As[cur ^ 1], tid);
      stage_tile(Bw, ldb, bn * 128, kn, Bs[cur ^ 1], tid);
    }
    short8 a[4], b[4];
#pragma unroll
    for (int mf = 0; mf < 4; ++mf)
      a[mf] = *(const short8*)&As[cur][(wr + mf * 16 + fr) * 32 + kg];
#pragma unroll
    for (int nf = 0; nf < 4; ++nf)
      b[nf] = *(const short8*)&Bs[cur][(wc + nf * 16 + fr) * 32 + kg];
#pragma unroll
    for (int mf = 0; mf < 4; ++mf)
#pragma unroll
      for (int nf = 0; nf < 4; ++nf)
        acc[mf][nf] = __builtin_amdgcn_mfma_f32_16x16x32_bf16(a[mf], b[nf], acc[mf][nf], 0, 0, 0);
    __syncthreads();
    cur ^= 1;
  }
  int r0 = bm * 128 + wr + (lane >> 4) * 4;
  int c0 = bn * 128 + wc + fr;
#pragma unroll
  for (int mf = 0; mf < 4; ++mf) {
#pragma unroll
    for (int nf = 0; nf < 4; ++nf) {
#pragma unroll
      for (int r = 0; r < 4; ++r) {
        int gr = r0 + mf * 16 + r;
        int gc = c0 + nf * 16;
        float v = acc[mf][nf][r];
        size_t idx = (size_t)gr * ldc + gc;
        if (EPI == 1) {
          ((u16*)C)[idx] = f2bf(v);
        } else {
          atomicAdd(&C[idx], v);
        }
      }
    }
  }
}

// ---------------- x_proj GEMM with fused causal dwconv(K=4)+SiLU on A ----------------
// A[m, d] = silu(conv(xz[:, d])[m]); also writes xs_bf. B = padded x_proj_w (128 x 2048).
// grid (16, 1, 8): bm x 1 x splitK. C = xdbl_l (2048 x 128), atomic.
__global__ __launch_bounds__(256) void xproj_conv_k(const u16* __restrict__ xzb,
    const float* __restrict__ cw, const float* __restrict__ cb,
    const u16* __restrict__ Bw, u16* __restrict__ xsb, float* __restrict__ xdbl_l) {
  __shared__ u16 As[128 * 32];
  __shared__ u16 Bs[128 * 32];
  int tid = threadIdx.x;
  int bm = blockIdx.x;
  int kb = blockIdx.z * 256;
  int lane = tid & 63, w = tid >> 6;
  int wr = (w >> 1) * 64, wc = (w & 1) * 64;
  int fr = lane & 15;
  int kg = (lane >> 4) * 8;
  f32x4 acc[4][4] = {};
  int r  = tid >> 1;          // 0..127 (m row within tile)
  int cc = (tid & 1) * 16;    // 0 or 16 (k col half)
  int m  = bm * 128 + r;
  int tseq = m & (SEQL - 1);
  for (int k0i = 0; k0i < 256; k0i += 32) {
    int k0 = kb + k0i;
    int d0 = k0 + cc;
    // conv weights/bias for 16 channels
    float4 cw4[16];
#pragma unroll
    for (int i = 0; i < 16; ++i) cw4[i] = *(const float4*)&cw[(d0 + i) * 4];
    float accv[16];
#pragma unroll
    for (int q = 0; q < 4; ++q) {
      float4 c4 = *(const float4*)&cb[d0 + q * 4];
      accv[q*4+0] = c4.x; accv[q*4+1] = c4.y; accv[q*4+2] = c4.z; accv[q*4+3] = c4.w;
    }
#pragma unroll
    for (int j = 0; j < 4; ++j) {
      int tt = tseq - 3 + j;
      if (tt >= 0) {
        const u16* src = &xzb[(size_t)(m - 3 + j) * 4096 + d0];
        short8 v0 = *(const short8*)src;
        short8 v1 = *(const short8*)(src + 8);
#pragma unroll
        for (int i = 0; i < 8; ++i)
          accv[i] += bf2f((u16)v0[i]) * ((const float*)&cw4[i])[j];
#pragma unroll
        for (int i = 0; i < 8; ++i)
          accv[8 + i] += bf2f((u16)v1[i]) * ((const float*)&cw4[8 + i])[j];
      }
    }
    short8 o0, o1;
#pragma unroll
    for (int i = 0; i < 8; ++i) {
      float s0 = accv[i]     / (1.f + __expf(-accv[i]));
      float s1 = accv[8 + i] / (1.f + __expf(-accv[8 + i]));
      o0[i] = (short)f2bf(s0);
      o1[i] = (short)f2bf(s1);
    }
    __syncthreads();   // previous iteration's LDS reads complete
    *(short8*)&As[r * 32 + cc]     = o0;
    *(short8*)&As[r * 32 + cc + 8] = o1;
    stage_tile(Bw, 2048, 0, k0, Bs, tid);
    // persist silu(conv) for the scan
    *(short8*)&xsb[(size_t)m * 2048 + d0]     = o0;
    *(short8*)&xsb[(size_t)m * 2048 + d0 + 8] = o1;
    __syncthreads();
    short8 a[4], b[4];
#pragma unroll
    for (int mf = 0; mf < 4; ++mf)
      a[mf] = *(const short8*)&As[(wr + mf * 16 + fr) * 32 + kg];
#pragma unroll
    for (int nf = 0; nf < 4; ++nf)
      b[nf] = *(const short8*)&Bs[(wc + nf * 16 + fr) * 32 + kg];
#pragma unroll
    for (int mf = 0; mf < 4; ++mf)
#pragma unroll
      for (int nf = 0; nf < 4; ++nf)
        acc[mf][nf] = __builtin_amdgcn_mfma_f32_16x16x32_bf16(a[mf], b[nf], acc[mf][nf], 0, 0, 0);
  }
  int r0 = bm * 128 + wr + (lane >> 4) * 4;
  int c0 = wc + fr;
#pragma unroll
  for (int mf = 0; mf < 4; ++mf)
#pragma unroll
    for (int nf = 0; nf < 4; ++nf)
#pragma unroll
      for (int rr = 0; rr < 4; ++rr) {
        int gr = r0 + mf * 16 + rr;
        int gc = c0 + nf * 16;
        atomicAdd(&xdbl_l[(size_t)gr * 128 + gc], acc[mf][nf][rr]);
      }
}

// ---------------- dt GEMM: dt = softplus(xdbl[:, :64] @ w_dt^T + bias) -> bf16 ----------------
// A = xdbl_l f32 (2048 x 128, cols 0..63), B = w_dt bf16 (2048 x 64). grid (16,16).
__global__ __launch_bounds__(256) void gemm_dt_k(const float* __restrict__ Af,
    const u16* __restrict__ Bw, const float* __restrict__ bias, u16* __restrict__ Cout) {
  __shared__ u16 As[128 * 32];
  __shared__ u16 Bs[128 * 32];
  int tid = threadIdx.x;
  int bm = blockIdx.x, bn = blockIdx.y;
  int lane = tid & 63, w = tid >> 6;
  int wr = (w >> 1) * 64, wc = (w & 1) * 64;
  int fr = lane & 15;
  int kg = (lane >> 4) * 8;
  f32x4 acc[4][4] = {};
  int r  = tid >> 1;
  int cc = (tid & 1) * 16;
  for (int k0 = 0; k0 < 64; k0 += 32) {
    const float* src = &Af[(size_t)(bm * 128 + r) * 128 + k0 + cc];
    float4 f0 = *(const float4*)&src[0];
    float4 f1 = *(const float4*)&src[4];
    float4 f2 = *(const float4*)&src[8];
    float4 f3 = *(const float4*)&src[12];
    short8 o0, o1;
    o0[0]=(short)f2bf(f0.x); o0[1]=(short)f2bf(f0.y); o0[2]=(short)f2bf(f0.z); o0[3]=(short)f2bf(f0.w);
    o0[4]=(short)f2bf(f1.x); o0[5]=(short)f2bf(f1.y); o0[6]=(short)f2bf(f1.z); o0[7]=(short)f2bf(f1.w);
    o1[0]=(short)f2bf(f2.x); o1[1]=(short)f2bf(f2.y); o1[2]=(short)f2bf(f2.z); o1[3]=(short)f2bf(f2.w);
    o1[4]=(short)f2bf(f3.x); o1[5]=(short)f2bf(f3.y); o1[6]=(short)f2bf(f3.z); o1[7]=(short)f2bf(f3.w);
    __syncthreads();
    *(short8*)&As[r * 32 + cc]     = o0;
    *(short8*)&As[r * 32 + cc + 8] = o1;
    stage_tile(Bw, 64, bn * 128, k0, Bs, tid);
    __syncthreads();
    short8 a[4], b[4];
#pragma unroll
    for (int mf = 0; mf < 4; ++mf)
      a[mf] = *(const short8*)&As[(wr + mf * 16 + fr) * 32 + kg];
#pragma unroll
    for (int nf = 0; nf < 4; ++nf)
      b[nf] = *(const short8*)&Bs[(wc + nf * 16 + fr) * 32 + kg];
#pragma unroll
    for (int mf = 0; mf < 4; ++mf)
#pragma unroll
      for (int nf = 0; nf < 4; ++nf)
        acc[mf][nf] = __builtin_amdgcn_mfma_f32_16x16x32_bf16(a[mf], b[nf], acc[mf][nf], 0, 0, 0);
  }
  int r0 = bm * 128 + wr + (lane >> 4) * 4;
  int c0 = bn * 128 + wc + fr;
#pragma unroll
  for (int mf = 0; mf < 4; ++mf)
#pragma unroll
    for (int nf = 0; nf < 4; ++nf)
#pragma unroll
      for (int rr = 0; rr < 4; ++rr) {
        int gr = r0 + mf * 16 + rr;
        int gc = c0 + nf * 16;
        float v = acc[mf][nf][rr] + bias[gc];
        v = (v > 20.f) ? v : log1pf(__expf(v));
        Cout[(size_t)gr * 2048 + gc] = f2bf(v);
      }
}

// ---------------- chunked selective scan ----------------
__global__ __launch_bounds__(256) void scan_part1(const u16* __restrict__ dtb,
    const u16* __restrict__ xsb, const float* __restrict__ xdbl,
    const float* __restrict__ Alog, float* __restrict__ PS) {
  int tid = threadIdx.x;
  int dg = blockIdx.x & 7;
  int ch = (blockIdx.x >> 3) & (NCH - 1);
  int b  = blockIdx.x >> 9;
  int d  = dg * 256 + tid;
  float Ar[16];
#pragma unroll
  for (int q = 0; q < 4; ++q) {
    float4 a = *(const float4*)&Alog[d * 16 + q * 4];
    Ar[q*4+0] = -__expf(a.x); Ar[q*4+1] = -__expf(a.y);
    Ar[q*4+2] = -__expf(a.z); Ar[q*4+3] = -__expf(a.w);
  }
  __shared__ float Bsh[CLEN][16];
  {
    int t = tid >> 4, n = tid & 15;
    int mm = b * SEQL + ch * CLEN + t;
    Bsh[t][n] = xdbl[mm * 128 + 64 + n];
  }
  __syncthreads();
  int mbase = b * SEQL + ch * CLEN;
  float dtv[CLEN], xv[CLEN];
#pragma unroll
  for (int t = 0; t < CLEN; ++t) dtv[t] = bf2f(dtb[(size_t)(mbase + t) * 2048 + d]);
#pragma unroll
  for (int t = 0; t < CLEN; ++t) xv[t] = bf2f(xsb[(size_t)(mbase + t) * 2048 + d]);
  float S[16];
#pragma unroll
  for (int n = 0; n < 16; ++n) S[n] = 0.f;
  float sumdt = 0.f;
  for (int t = 0; t < CLEN; ++t) {
    sumdt += dtv[t];
    float dx = dtv[t] * xv[t];
    float4 B0 = *(const float4*)&Bsh[t][0];
    float4 B1 = *(const float4*)&Bsh[t][4];
    float4 B2 = *(const float4*)&Bsh[t][8];
    float4 B3 = *(const float4*)&Bsh[t][12];
    const float* Bp[4] = {(const float*)&B0, (const float*)&B1, (const float*)&B2, (const float*)&B3};
#pragma unroll
    for (int n = 0; n < 16; ++n)
      S[n] = __expf(dtv[t] * Ar[n]) * S[n] + dx * Bp[n >> 2][n & 3];
  }
  float* p = PS + ((size_t)(b * NCH + ch) * 2048 + d) * 32;
#pragma unroll
  for (int n = 0; n < 16; ++n) p[n] = S[n];
#pragma unroll
  for (int n = 0; n < 16; ++n) p[16 + n] = __expf(Ar[n] * sumdt);
}

__global__ __launch_bounds__(256) void scan_prefix(const float* __restrict__ PS,
                                                   float* __restrict__ Hstart) {
  int id = blockIdx.x * 256 + threadIdx.x;   // 2*2048*16 = 65536
  int n = id & 15;
  int d = (id >> 4) & 2047;
  int b = id >> 15;
  size_t sbase = ((size_t)b * NCH) * 2048 * 32 + (size_t)d * 32 + n;
  size_t hbase = ((size_t)b * NCH) * 2048 * 16 + (size_t)d * 16 + n;
  float h = 0.f;
#pragma unroll 8
  for (int ch = 0; ch < NCH; ++ch) {
    Hstart[hbase + (size_t)ch * (2048 * 16)] = h;
    float S = PS[sbase + (size_t)ch * (2048 * 32)];
    float P = PS[sbase + (size_t)ch * (2048 * 32) + 16];
    h = fmaf(P, h, S);
  }
}

__global__ __launch_bounds__(256) void scan_part2(const u16* __restrict__ dtb,
    const u16* __restrict__ xsb, const float* __restrict__ xdbl,
    const float* __restrict__ Alog, const float* __restrict__ Dv,
    const u16* __restrict__ xzb, const float* __restrict__ Hstart,
    u16* __restrict__ yg) {
  int tid = threadIdx.x;
  int dg = blockIdx.x & 7;
  int ch = (blockIdx.x >> 3) & (NCH - 1);
  int b  = blockIdx.x >> 9;
  int d  = dg * 256 + tid;
  float Ar[16];
#pragma unroll
  for (int q = 0; q < 4; ++q) {
    float4 a = *(const float4*)&Alog[d * 16 + q * 4];
    Ar[q*4+0] = -__expf(a.x); Ar[q*4+1] = -__expf(a.y);
    Ar[q*4+2] = -__expf(a.z); Ar[q*4+3] = -__expf(a.w);
  }
  float Dvd = Dv[d];
  __shared__ float BCs[CLEN][32];
  {
    int t = tid >> 5, n = tid & 31;
    int mm = b * SEQL + ch * CLEN + t;
    BCs[t][n] = xdbl[mm * 128 + 64 + n];
    BCs[t + 8][n] = xdbl[(mm + 8) * 128 + 64 + n];
  }
  const float* hs = Hstart + ((size_t)(b * NCH + ch) * 2048 + d) * 16;
  float h[16];
#pragma unroll
  for (int q = 0; q < 4; ++q) {
    float4 hv = *(const float4*)&hs[q * 4];
    h[q*4+0] = hv.x; h[q*4+1] = hv.y; h[q*4+2] = hv.z; h[q*4+3] = hv.w;
  }
  int mbase = b * SEQL + ch * CLEN;
  float dtv[CLEN], xv[CLEN], zv[CLEN];
#pragma unroll
  for (int t = 0; t < CLEN; ++t) dtv[t] = bf2f(dtb[(size_t)(mbase + t) * 2048 + d]);
#pragma unroll
  for (int t = 0; t < CLEN; ++t) xv[t] = bf2f(xsb[(size_t)(mbase + t) * 2048 + d]);
#pragma unroll
  for (int t = 0; t < CLEN; ++t) zv[t] = bf2f(xzb[(size_t)(mbase + t) * 4096 + 2048 + d]);
  __syncthreads();
  for (int t = 0; t < CLEN; ++t) {
    float dx = dtv[t] * xv[t];
    float4 B0 = *(const float4*)&BCs[t][0];
    float4 B1 = *(const float4*)&BCs[t][4];
    float4 B2 = *(const float4*)&BCs[t][8];
    float4 B3 = *(const float4*)&BCs[t][12];
    float4 C0 = *(const float4*)&BCs[t][16];
    float4 C1 = *(const float4*)&BCs[t][20];
    float4 C2 = *(const float4*)&BCs[t][24];
    float4 C3 = *(const float4*)&BCs[t][28];
    const float* Bp[4] = {(const float*)&B0, (const float*)&B1, (const float*)&B2, (const float*)&B3};
    const float* Cp[4] = {(const float*)&C0, (const float*)&C1, (const float*)&C2, (const float*)&C3};
#pragma unroll
    for (int n = 0; n < 16; ++n)
      h[n] = __expf(dtv[t] * Ar[n]) * h[n] + dx * Bp[n >> 2][n & 3];
    float y0 = 0.f, y1 = 0.f, y2 = 0.f, y3 = 0.f;
#pragma unroll
    for (int n = 0; n < 4; ++n) {
      y0 += h[n]      * Cp[0][n];
      y1 += h[4 + n]  * Cp[1][n];
      y2 += h[8 + n]  * Cp[2][n];
      y3 += h[12 + n] * Cp[3][n];
    }
    float y = (y0 + y1) + (y2 + y3) + xv[t] * Dvd;
    float sz = zv[t] / (1.f + __expf(-zv[t]));
    yg[(size_t)(mbase + t) * 2048 + d] = f2bf(y * sz);
  }
}

// ---------------- head ----------------
__global__ __launch_bounds__(256) void final_ln_last_k(const float* __restrict__ xb,
    const float* __restrict__ w, const float* __restrict__ b, float* __restrict__ out) {
  int bb = blockIdx.x, tid = threadIdx.x;
  const float* x = xb + (size_t)(bb * 1024 + 1023) * 1024;
  float4 v = ((const float4*)x)[tid];
  float s = v.x + v.y + v.z + v.w;
  float q = v.x*v.x + v.y*v.y + v.z*v.z + v.w*v.w;
  for (int o = 32; o; o >>= 1) { s += __shfl_down(s, o); q += __shfl_down(q, o); }
  __shared__ float sb[4], qb[4];
  int wv = tid >> 6, lane = tid & 63;
  if (lane == 0) { sb[wv] = s; qb[wv] = q; }
  __syncthreads();
  s = sb[0] + sb[1] + sb[2] + sb[3];
  q = qb[0] + qb[1] + qb[2] + qb[3];
  float mean = s * (1.f / 1024.f);
  float rstd = rsqrtf(q * (1.f / 1024.f) - mean * mean + 1e-5f);
  float4 wv4 = ((const float4*)w)[tid];
  float4 bv4 = ((const float4*)b)[tid];
  float4 o;
  o.x = (v.x - mean) * rstd * wv4.x + bv4.x;
  o.y = (v.y - mean) * rstd * wv4.y + bv4.y;
  o.z = (v.z - mean) * rstd * wv4.z + bv4.z;
  o.w = (v.w - mean) * rstd * wv4.w + bv4.w;
  ((float4*)(out + bb * 1024))[tid] = o;
}

__global__ __launch_bounds__(256) void gemv_head1_k(const float* __restrict__ X,
    const float* __restrict__ W, const float* __restrict__ bias, float* __restrict__ out) {
  int gw = (blockIdx.x * 256 + threadIdx.x) >> 6;  // 0..4095
  int lane = threadIdx.x & 63;
  int b = gw >> 11, j = gw & 2047;
  const float* x = X + b * 1024;
  const float* w = W + (size_t)j * 1024;
  float s = 0.f;
#pragma unroll
  for (int q = 0; q < 4; ++q) {
    int col = q * 256 + lane * 4;
    float4 xv = *(const float4*)&x[col];
    float4 wv = *(const float4*)&w[col];
    s += xv.x*wv.x + xv.y*wv.y + xv.z*wv.z + xv.w*wv.w;
  }
  for (int o = 32; o; o >>= 1) s += __shfl_down(s, o);
  if (lane == 0) out[gw] = s + bias[j];
}

__global__ __launch_bounds__(256) void ln_gelu_k(const float* __restrict__ X,
    const float* __restrict__ w, const float* __restrict__ b, float* __restrict__ out) {
  int row = blockIdx.x, tid = threadIdx.x;
  const float* x = X + (size_t)row * 2048;
  float4 v0 = ((const float4*)x)[tid];
  float4 v1 = ((const float4*)x)[tid + 256];
  float s = v0.x+v0.y+v0.z+v0.w + v1.x+v1.y+v1.z+v1.w;
  float q = v0.x*v0.x+v0.y*v0.y+v0.z*v0.z+v0.w*v0.w
          + v1.x*v1.x+v1.y*v1.y+v1.z*v1.z+v1.w*v1.w;
  for (int o = 32; o; o >>= 1) { s += __shfl_down(s, o); q += __shfl_down(q, o); }
  __shared__ float sb[4], qb[4];
  int wv = tid >> 6, lane = tid & 63;
  if (lane == 0) { sb[wv] = s; qb[wv] = q; }
  __syncthreads();
  s = sb[0] + sb[1] + sb[2] + sb[3];
  q = qb[0] + qb[1] + qb[2] + qb[3];
  float mean = s * (1.f / 2048.f);
  float rstd = rsqrtf(q * (1.f / 2048.f) - mean * mean + 1e-5f);
  float* o0 = out + (size_t)row * 2048;
#pragma unroll
  for (int h = 0; h < 2; ++h) {
    float4 v = h ? v1 : v0;
    int c0 = tid * 4 + h * 1024;
    float4 wv4 = *(const float4*)&w[c0];
    float4 bv4 = *(const float4*)&b[c0];
    float4 g;
    g.x = (v.x - mean) * rstd * wv4.x + bv4.x;
    g.y = (v.y - mean) * rstd * wv4.y + bv4.y;
    g.z = (v.z - mean) * rstd * wv4.z + bv4.z;
    g.w = (v.w - mean) * rstd * wv4.w + bv4.w;
    g.x = 0.5f * g.x * (1.f + erff(g.x * 0.70710678f));
    g.y = 0.5f * g.y * (1.f + erff(g.y * 0.70710678f));
    g.z = 0.5f * g.z * (1.f + erff(g.z * 0.70710678f));
    g.w = 0.5f * g.w * (1.f + erff(g.w * 0.70710678f));
    *(float4*)&o0[c0] = g;
  }
}

__global__ __launch_bounds__(256) void gemv_head2_k(const float* __restrict__ X,
    const float* __restrict__ W, const float* __restrict__ bias, float* __restrict__ out) {
  int gw = (blockIdx.x * 256 + threadIdx.x) >> 6;  // 0..1999
  int lane = threadIdx.x & 63;
  int b = (gw >= 1000) ? 1 : 0;
  int j = gw - b * 1000;
  const float* x = X + b * 2048;
  const float* w = W + (size_t)j * 2048;
  float s = 0.f;
#pragma unroll
  for (int q = 0; q < 8; ++q) {
    int col = q * 256 + lane * 4;
    float4 xv = *(const float4*)&x[col];
    float4 wv = *(const float4*)&w[col];
    s += xv.x*wv.x + xv.y*wv.y + xv.z*wv.z + xv.w*wv.w;
  }
  for (int o = 32; o; o >>= 1) s += __shfl_down(s, o);
  if (lane == 0) out[gw] = s + bias[j];
}

// ---------------- launch ----------------
extern "C" void kernel_launch(void* const* d_in, const int* in_sizes, int n_in,
                              void* d_out, int out_size, void* d_ws, size_t ws_size,
                              hipStream_t stream) {
  const float* x_in = (const float*)d_in[0];
  const float* lnw  = (const float*)d_in[1];
  const float* lnb  = (const float*)d_in[2];
  const float* ipw  = (const float*)d_in[3];
  const float* cw   = (const float*)d_in[4];
  const float* cb   = (const float*)d_in[5];
  const float* xpw  = (const float*)d_in[6];
  const float* dpw  = (const float*)d_in[7];
  const float* dpb  = (const float*)d_in[8];
  const float* Alog = (const float*)d_in[9];
  const float* Dv   = (const float*)d_in[10];
  const float* opw  = (const float*)d_in[11];
  const float* fnw  = (const float*)d_in[12];
  const float* fnb  = (const float*)d_in[13];
  const float* h1w  = (const float*)d_in[14];
  const float* h1b  = (const float*)d_in[15];
  const float* hlnw = (const float*)d_in[16];
  const float* hlnb = (const float*)d_in[17];
  const float* h2w  = (const float*)d_in[18];
  const float* h2b  = (const float*)d_in[19];
  float* out = (float*)d_out;

  char* ws = (char*)d_ws;
  size_t off = 0;
  auto alloc = [&](size_t bytes) -> void* {
    void* p = ws + off; off += (bytes + 255) & ~(size_t)255; return p;
  };
  float* x_buf   = (float*)alloc((size_t)MTOK * DMODEL * 4);
  u16*   xn_bf   = (u16*)  alloc((size_t)MTOK * DMODEL * 2);
  u16*   xz_bf   = (u16*)  alloc((size_t)MTOK * 2 * DINNER * 2);
  u16*   xs_bf   = (u16*)  alloc((size_t)MTOK * DINNER * 2);
  float* xdbl4   = (float*)alloc((size_t)NLAYER * MTOK * 128 * 4);
  u16*   dtb     = (u16*)  alloc((size_t)MTOK * DINNER * 2);
  u16*   yg_bf   = (u16*)  alloc((size_t)MTOK * DINNER * 2);
  u16*   w_ip4   = (u16*)  alloc((size_t)NLAYER * 2 * DINNER * DMODEL * 2);
  u16*   w_xp4   = (u16*)  alloc((size_t)NLAYER * 128 * DINNER * 2);
  u16*   w_dt4   = (u16*)  alloc((size_t)NLAYER * DINNER * DTRANK * 2);
  u16*   w_op4   = (u16*)  alloc((size_t)NLAYER * DMODEL * DINNER * 2);
  float* PS      = (float*)alloc((size_t)NBATCH * NCH * DINNER * 32 * 4);
  float* Hstart  = (float*)alloc((size_t)NBATCH * NCH * DINNER * 16 * 4);
  float* lastn   = (float*)alloc(2 * 1024 * 4);
  float* hpre    = (float*)alloc(2 * 2048 * 4);
  float* hbuf    = (float*)alloc(2 * 2048 * 4);

  hipMemcpyAsync(x_buf, x_in, (size_t)MTOK * DMODEL * 4, hipMemcpyDeviceToDevice, stream);
  { dim3 g(4096, 4); f32_to_bf16_l<<<g, 256, 0, stream>>>(ipw, w_ip4, 2 * DINNER * DMODEL); }
  { dim3 g(256, 4);  cvt_pad_xproj_l<<<g, 256, 0, stream>>>(xpw, w_xp4); }
  { dim3 g(128, 4);  f32_to_bf16_l<<<g, 256, 0, stream>>>(dpw, w_dt4, DINNER * DTRANK); }
  { dim3 g(2048, 4); f32_to_bf16_l<<<g, 256, 0, stream>>>(opw, w_op4, DMODEL * DINNER); }
  hipMemsetAsync(xdbl4, 0, (size_t)NLAYER * MTOK * 128 * 4, stream);

  for (int i = 0; i < NLAYER; ++i) {
    float* xdbl_l = xdbl4 + (size_t)i * MTOK * 128;
    ln_to_bf16_k<<<MTOK, 256, 0, stream>>>(x_buf, lnw + i * DMODEL, lnb + i * DMODEL, xn_bf);
    { dim3 g(16, 32, 1);
      gemm_bt<1><<<g, 256, 0, stream>>>(xn_bf, w_ip4 + (size_t)i * 2 * DINNER * DMODEL,
                                        (float*)xz_bf, 1024, 1024, 4096, 1024); }
    { dim3 g(16, 1, 8);
      xproj_conv_k<<<g, 256, 0, stream>>>(xz_bf, cw + (size_t)i * DINNER * 4, cb + i * DINNER,
                                          w_xp4 + (size_t)i * 128 * DINNER, xs_bf, xdbl_l); }
    { dim3 g(16, 16, 1);
      gemm_dt_k<<<g, 256, 0, stream>>>(xdbl_l, w_dt4 + (size_t)i * DINNER * DTRANK,
                                       dpb + i * DINNER, dtb); }
    scan_part1<<<1024, 256, 0, stream>>>(dtb, xs_bf, xdbl_l, Alog + (size_t)i * DINNER * DSTATE, PS);
    scan_prefix<<<256, 256, 0, stream>>>(PS, Hstart);
    scan_part2<<<1024, 256, 0, stream>>>(dtb, xs_bf, xdbl_l, Alog + (size_t)i * DINNER * DSTATE,
                                         Dv + i * DINNER, xz_bf, Hstart, yg_bf);
    { dim3 g(16, 8, 2);
      gemm_bt<3><<<g, 256, 0, stream>>>(yg_bf, w_op4 + (size_t)i * DMODEL * DINNER,
                                        x_buf, 2048, 2048, 1024, 1024); }
  }
  final_ln_last_k<<<2, 256, 0, stream>>>(x_buf, fnw, fnb, lastn);
  gemv_head1_k<<<1024, 256, 0, stream>>>(lastn, h1w, h1b, hpre);
  ln_gelu_k<<<2, 256, 0, stream>>>(hpre, hlnw, hlnb, hbuf);
  gemv_head2_k<<<500, 256, 0, stream>>>(hbuf, h2w, h2b, out);
  (void)in_sizes; (void)n_in; (void)out_size; (void)ws_size;
}

// Round 5
// 736.230 us; speedup vs baseline: 2.0448x; 1.0420x over previous
//
#include <hip/hip_runtime.h>

typedef unsigned short u16;
using short8 = __attribute__((ext_vector_type(8))) short;
using f32x4  = __attribute__((ext_vector_type(4))) float;

#define NLAYER 4
#define DMODEL 1024
#define DSTATE 16
#define DINNER 2048
#define DTRANK 64
#define SEQL   1024
#define NBATCH 2
#define MTOK   2048   /* NBATCH*SEQL */
#define NCH    64     /* scan chunks per sequence */
#define CLEN   16     /* timesteps per chunk: NCH*CLEN == SEQL */

__device__ __forceinline__ u16 f2bf(float f) {
  union { float f; unsigned int u; } cv; cv.f = f;
  return (u16)((cv.u + 0x7FFFu + ((cv.u >> 16) & 1u)) >> 16);
}
__device__ __forceinline__ float bf2f(u16 v) {
  union { unsigned int u; float f; } cv; cv.u = ((unsigned int)v) << 16; return cv.f;
}

// ---------------- batched weight conversion (all layers in one launch) ----------------
__global__ __launch_bounds__(256) void f32_to_bf16_l(const float* __restrict__ src,
                                                     u16* __restrict__ dst, int nper) {
  int l = blockIdx.y;
  int i4 = (blockIdx.x * 256 + threadIdx.x) * 4;
  if (i4 >= nper) return;
  float4 v = *(const float4*)&src[(size_t)l * nper + i4];
  ushort4 o; o.x = f2bf(v.x); o.y = f2bf(v.y); o.z = f2bf(v.z); o.w = f2bf(v.w);
  *(ushort4*)&dst[(size_t)l * nper + i4] = o;
}

// x_proj_w (L x 96 x 2048) -> padded (L x 128 x 2048) bf16
__global__ __launch_bounds__(256) void cvt_pad_xproj_l(const float* __restrict__ src,
                                                       u16* __restrict__ dst) {
  int l = blockIdx.y;
  int i4 = (blockIdx.x * 256 + threadIdx.x) * 4;   // 128*2048 per layer
  int row = i4 >> 11, col = i4 & 2047;
  float4 v = make_float4(0.f, 0.f, 0.f, 0.f);
  if (row < 96) v = *(const float4*)&src[(size_t)l * 96 * 2048 + row * 2048 + col];
  ushort4 o; o.x = f2bf(v.x); o.y = f2bf(v.y); o.z = f2bf(v.z); o.w = f2bf(v.w);
  *(ushort4*)&dst[(size_t)l * 128 * 2048 + i4] = o;
}

// ---------------- LayerNorm -> bf16 (row = 1024) ----------------
__global__ __launch_bounds__(256) void ln_to_bf16_k(const float* __restrict__ X,
    const float* __restrict__ w, const float* __restrict__ b, u16* __restrict__ out) {
  int row = blockIdx.x, tid = threadIdx.x;
  const float* x = X + (size_t)row * 1024;
  float4 v = ((const float4*)x)[tid];
  float s = v.x + v.y + v.z + v.w;
  float q = v.x*v.x + v.y*v.y + v.z*v.z + v.w*v.w;
  for (int o = 32; o; o >>= 1) { s += __shfl_down(s, o); q += __shfl_down(q, o); }
  __shared__ float sb[4], qb[4];
  int wv = tid >> 6, lane = tid & 63;
  if (lane == 0) { sb[wv] = s; qb[wv] = q; }
  __syncthreads();
  s = sb[0] + sb[1] + sb[2] + sb[3];
  q = qb[0] + qb[1] + qb[2] + qb[3];
  float mean = s * (1.f / 1024.f);
  float var  = q * (1.f / 1024.f) - mean * mean;
  float rstd = rsqrtf(var + 1e-5f);
  float4 wv4 = ((const float4*)w)[tid];
  float4 bv4 = ((const float4*)b)[tid];
  ushort4 o4;
  o4.x = f2bf((v.x - mean) * rstd * wv4.x + bv4.x);
  o4.y = f2bf((v.y - mean) * rstd * wv4.y + bv4.y);
  o4.z = f2bf((v.z - mean) * rstd * wv4.z + bv4.z);
  o4.w = f2bf((v.w - mean) * rstd * wv4.w + bv4.w);
  ((ushort4*)(out + (size_t)row * 1024))[tid] = o4;
}

// ---------------- MFMA GEMM: C[M,N] = A[M,K] * W[N,K]^T ----------------
__device__ __forceinline__ void stage_tile(const u16* G, int ld, int row0, int k0,
                                           u16* S, int tid) {
  int w = tid >> 6;
#pragma unroll
  for (int j = 0; j < 2; ++j) {
    int t = tid + j * 256;
    int r = t >> 2;
    int c = (t & 3) << 3;
    const u16* g = G + (size_t)(row0 + r) * ld + (k0 + c);
    u16* s = S + w * 512 + j * 2048;  // wave-uniform base; HW adds lane*16B
    __builtin_amdgcn_global_load_lds((const __attribute__((address_space(1))) void*)g,
                                     (__attribute__((address_space(3))) void*)s,
                                     16, 0, 0);
  }
}

// 2-phase double-buffered. EPI: 1 = bf16 store, 3 = atomicAdd f32
template<int EPI>
__global__ __launch_bounds__(256) void gemm_bt(const u16* __restrict__ A,
    const u16* __restrict__ Bw, float* __restrict__ C,
    int lda, int ldb, int ldc, int kchunk) {
  __shared__ u16 As[2][128 * 32];
  __shared__ u16 Bs[2][128 * 32];
  int tid = threadIdx.x;
  int bm = blockIdx.x, bn = blockIdx.y;
  int kb = blockIdx.z * kchunk, ke = kb + kchunk;
  int lane = tid & 63, w = tid >> 6;
  int wr = (w >> 1) * 64, wc = (w & 1) * 64;
  int fr = lane & 15;
  int kg = (lane >> 4) * 8;
  f32x4 acc[4][4] = {};
  int cur = 0;
  stage_tile(A, lda, bm * 128, kb, As[0], tid);
  stage_tile(Bw, ldb, bn * 128, kb, Bs[0], tid);
  __syncthreads();
  for (int k0 = kb; k0 < ke; k0 += 32) {
    int kn = k0 + 32;
    if (kn < ke) {
      stage_tile(A, lda, bm * 128, kn, As[cur ^ 1], tid);
      stage_tile(Bw, ldb, bn * 128, kn, Bs[cur ^ 1], tid);
    }
    short8 a[4], b[4];
#pragma unroll
    for (int mf = 0; mf < 4; ++mf)
      a[mf] = *(const short8*)&As[cur][(wr + mf * 16 + fr) * 32 + kg];
#pragma unroll
    for (int nf = 0; nf < 4; ++nf)
      b[nf] = *(const short8*)&Bs[cur][(wc + nf * 16 + fr) * 32 + kg];
#pragma unroll
    for (int mf = 0; mf < 4; ++mf)
#pragma unroll
      for (int nf = 0; nf < 4; ++nf)
        acc[mf][nf] = __builtin_amdgcn_mfma_f32_16x16x32_bf16(a[mf], b[nf], acc[mf][nf], 0, 0, 0);
    __syncthreads();
    cur ^= 1;
  }
  int r0 = bm * 128 + wr + (lane >> 4) * 4;
  int c0 = bn * 128 + wc + fr;
#pragma unroll
  for (int mf = 0; mf < 4; ++mf) {
#pragma unroll
    for (int nf = 0; nf < 4; ++nf) {
#pragma unroll
      for (int r = 0; r < 4; ++r) {
        int gr = r0 + mf * 16 + r;
        int gc = c0 + nf * 16;
        float v = acc[mf][nf][r];
        size_t idx = (size_t)gr * ldc + gc;
        if (EPI == 1) {
          ((u16*)C)[idx] = f2bf(v);
        } else {
          atomicAdd(&C[idx], v);
        }
      }
    }
  }
}

// ---------------- causal depthwise conv (K=4) + SiLU, bf16 in/out ----------------
__global__ __launch_bounds__(256) void conv_silu_k(const u16* __restrict__ xzb,
    const float* __restrict__ cw, const float* __restrict__ cb,
    u16* __restrict__ xsb) {
  int idx = blockIdx.x * 256 + threadIdx.x;  // 2048 * 512
  int m = idx >> 9;
  int d = (idx & 511) << 2;
  int t = m & (SEQL - 1);
  float4 w0 = *(const float4*)&cw[(d + 0) * 4];
  float4 w1 = *(const float4*)&cw[(d + 1) * 4];
  float4 w2 = *(const float4*)&cw[(d + 2) * 4];
  float4 w3 = *(const float4*)&cw[(d + 3) * 4];
  float4 acc = *(const float4*)&cb[d];
#pragma unroll
  for (int j = 0; j < 4; ++j) {
    int tt = t - 3 + j;
    if (tt >= 0) {
      ushort4 xv = *(const ushort4*)&xzb[(size_t)(m - 3 + j) * 4096 + d];
      acc.x += bf2f(xv.x) * ((const float*)&w0)[j];
      acc.y += bf2f(xv.y) * ((const float*)&w1)[j];
      acc.z += bf2f(xv.z) * ((const float*)&w2)[j];
      acc.w += bf2f(xv.w) * ((const float*)&w3)[j];
    }
  }
  float4 o;
  o.x = acc.x / (1.f + __expf(-acc.x));
  o.y = acc.y / (1.f + __expf(-acc.y));
  o.z = acc.z / (1.f + __expf(-acc.z));
  o.w = acc.w / (1.f + __expf(-acc.w));
  ushort4 ob; ob.x = f2bf(o.x); ob.y = f2bf(o.y); ob.z = f2bf(o.z); ob.w = f2bf(o.w);
  *(ushort4*)&xsb[(size_t)m * 2048 + d] = ob;
}

// ---------------- dt GEMM: dt = softplus(xdbl[:, :64] @ w_dt^T + bias) -> bf16 ----------------
// A = xdbl_l f32 (2048 x 128, cols 0..63), B = w_dt bf16 (2048 x 64). grid (16,16).
__global__ __launch_bounds__(256) void gemm_dt_k(const float* __restrict__ Af,
    const u16* __restrict__ Bw, const float* __restrict__ bias, u16* __restrict__ Cout) {
  __shared__ u16 As[128 * 32];
  __shared__ u16 Bs[128 * 32];
  int tid = threadIdx.x;
  int bm = blockIdx.x, bn = blockIdx.y;
  int lane = tid & 63, w = tid >> 6;
  int wr = (w >> 1) * 64, wc = (w & 1) * 64;
  int fr = lane & 15;
  int kg = (lane >> 4) * 8;
  f32x4 acc[4][4] = {};
  int r  = tid >> 1;
  int cc = (tid & 1) * 16;
  for (int k0 = 0; k0 < 64; k0 += 32) {
    const float* src = &Af[(size_t)(bm * 128 + r) * 128 + k0 + cc];
    float4 f0 = *(const float4*)&src[0];
    float4 f1 = *(const float4*)&src[4];
    float4 f2 = *(const float4*)&src[8];
    float4 f3 = *(const float4*)&src[12];
    short8 o0, o1;
    o0[0]=(short)f2bf(f0.x); o0[1]=(short)f2bf(f0.y); o0[2]=(short)f2bf(f0.z); o0[3]=(short)f2bf(f0.w);
    o0[4]=(short)f2bf(f1.x); o0[5]=(short)f2bf(f1.y); o0[6]=(short)f2bf(f1.z); o0[7]=(short)f2bf(f1.w);
    o1[0]=(short)f2bf(f2.x); o1[1]=(short)f2bf(f2.y); o1[2]=(short)f2bf(f2.z); o1[3]=(short)f2bf(f2.w);
    o1[4]=(short)f2bf(f3.x); o1[5]=(short)f2bf(f3.y); o1[6]=(short)f2bf(f3.z); o1[7]=(short)f2bf(f3.w);
    __syncthreads();
    *(short8*)&As[r * 32 + cc]     = o0;
    *(short8*)&As[r * 32 + cc + 8] = o1;
    stage_tile(Bw, 64, bn * 128, k0, Bs, tid);
    __syncthreads();
    short8 a[4], b[4];
#pragma unroll
    for (int mf = 0; mf < 4; ++mf)
      a[mf] = *(const short8*)&As[(wr + mf * 16 + fr) * 32 + kg];
#pragma unroll
    for (int nf = 0; nf < 4; ++nf)
      b[nf] = *(const short8*)&Bs[(wc + nf * 16 + fr) * 32 + kg];
#pragma unroll
    for (int mf = 0; mf < 4; ++mf)
#pragma unroll
      for (int nf = 0; nf < 4; ++nf)
        acc[mf][nf] = __builtin_amdgcn_mfma_f32_16x16x32_bf16(a[mf], b[nf], acc[mf][nf], 0, 0, 0);
  }
  int r0 = bm * 128 + wr + (lane >> 4) * 4;
  int c0 = bn * 128 + wc + fr;
#pragma unroll
  for (int mf = 0; mf < 4; ++mf)
#pragma unroll
    for (int nf = 0; nf < 4; ++nf)
#pragma unroll
      for (int rr = 0; rr < 4; ++rr) {
        int gr = r0 + mf * 16 + rr;
        int gc = c0 + nf * 16;
        float v = acc[mf][nf][rr] + bias[gc];
        v = (v > 20.f) ? v : log1pf(__expf(v));
        Cout[(size_t)gr * 2048 + gc] = f2bf(v);
      }
}

// ---------------- chunked selective scan ----------------
__global__ __launch_bounds__(256) void scan_part1(const u16* __restrict__ dtb,
    const u16* __restrict__ xsb, const float* __restrict__ xdbl,
    const float* __restrict__ Alog, float* __restrict__ PS) {
  int tid = threadIdx.x;
  int dg = blockIdx.x & 7;
  int ch = (blockIdx.x >> 3) & (NCH - 1);
  int b  = blockIdx.x >> 9;
  int d  = dg * 256 + tid;
  float Ar[16];
#pragma unroll
  for (int q = 0; q < 4; ++q) {
    float4 a = *(const float4*)&Alog[d * 16 + q * 4];
    Ar[q*4+0] = -__expf(a.x); Ar[q*4+1] = -__expf(a.y);
    Ar[q*4+2] = -__expf(a.z); Ar[q*4+3] = -__expf(a.w);
  }
  __shared__ float Bsh[CLEN][16];
  {
    int t = tid >> 4, n = tid & 15;
    int mm = b * SEQL + ch * CLEN + t;
    Bsh[t][n] = xdbl[mm * 128 + 64 + n];
  }
  __syncthreads();
  int mbase = b * SEQL + ch * CLEN;
  float dtv[CLEN], xv[CLEN];
#pragma unroll
  for (int t = 0; t < CLEN; ++t) dtv[t] = bf2f(dtb[(size_t)(mbase + t) * 2048 + d]);
#pragma unroll
  for (int t = 0; t < CLEN; ++t) xv[t] = bf2f(xsb[(size_t)(mbase + t) * 2048 + d]);
  float S[16];
#pragma unroll
  for (int n = 0; n < 16; ++n) S[n] = 0.f;
  float sumdt = 0.f;
  for (int t = 0; t < CLEN; ++t) {
    sumdt += dtv[t];
    float dx = dtv[t] * xv[t];
    float4 B0 = *(const float4*)&Bsh[t][0];
    float4 B1 = *(const float4*)&Bsh[t][4];
    float4 B2 = *(const float4*)&Bsh[t][8];
    float4 B3 = *(const float4*)&Bsh[t][12];
    const float* Bp[4] = {(const float*)&B0, (const float*)&B1, (const float*)&B2, (const float*)&B3};
#pragma unroll
    for (int n = 0; n < 16; ++n)
      S[n] = __expf(dtv[t] * Ar[n]) * S[n] + dx * Bp[n >> 2][n & 3];
  }
  float* p = PS + ((size_t)(b * NCH + ch) * 2048 + d) * 32;
#pragma unroll
  for (int n = 0; n < 16; ++n) p[n] = S[n];
#pragma unroll
  for (int n = 0; n < 16; ++n) p[16 + n] = __expf(Ar[n] * sumdt);
}

__global__ __launch_bounds__(256) void scan_prefix(const float* __restrict__ PS,
                                                   float* __restrict__ Hstart) {
  int id = blockIdx.x * 256 + threadIdx.x;   // 2*2048*16 = 65536
  int n = id & 15;
  int d = (id >> 4) & 2047;
  int b = id >> 15;
  size_t sbase = ((size_t)b * NCH) * 2048 * 32 + (size_t)d * 32 + n;
  size_t hbase = ((size_t)b * NCH) * 2048 * 16 + (size_t)d * 16 + n;
  float h = 0.f;
#pragma unroll 8
  for (int ch = 0; ch < NCH; ++ch) {
    Hstart[hbase + (size_t)ch * (2048 * 16)] = h;
    float S = PS[sbase + (size_t)ch * (2048 * 32)];
    float P = PS[sbase + (size_t)ch * (2048 * 32) + 16];
    h = fmaf(P, h, S);
  }
}

__global__ __launch_bounds__(256) void scan_part2(const u16* __restrict__ dtb,
    const u16* __restrict__ xsb, const float* __restrict__ xdbl,
    const float* __restrict__ Alog, const float* __restrict__ Dv,
    const u16* __restrict__ xzb, const float* __restrict__ Hstart,
    u16* __restrict__ yg) {
  int tid = threadIdx.x;
  int dg = blockIdx.x & 7;
  int ch = (blockIdx.x >> 3) & (NCH - 1);
  int b  = blockIdx.x >> 9;
  int d  = dg * 256 + tid;
  float Ar[16];
#pragma unroll
  for (int q = 0; q < 4; ++q) {
    float4 a = *(const float4*)&Alog[d * 16 + q * 4];
    Ar[q*4+0] = -__expf(a.x); Ar[q*4+1] = -__expf(a.y);
    Ar[q*4+2] = -__expf(a.z); Ar[q*4+3] = -__expf(a.w);
  }
  float Dvd = Dv[d];
  __shared__ float BCs[CLEN][32];
  {
    int t = tid >> 5, n = tid & 31;
    int mm = b * SEQL + ch * CLEN + t;
    BCs[t][n] = xdbl[mm * 128 + 64 + n];
    BCs[t + 8][n] = xdbl[(mm + 8) * 128 + 64 + n];
  }
  const float* hs = Hstart + ((size_t)(b * NCH + ch) * 2048 + d) * 16;
  float h[16];
#pragma unroll
  for (int q = 0; q < 4; ++q) {
    float4 hv = *(const float4*)&hs[q * 4];
    h[q*4+0] = hv.x; h[q*4+1] = hv.y; h[q*4+2] = hv.z; h[q*4+3] = hv.w;
  }
  int mbase = b * SEQL + ch * CLEN;
  float dtv[CLEN], xv[CLEN], zv[CLEN];
#pragma unroll
  for (int t = 0; t < CLEN; ++t) dtv[t] = bf2f(dtb[(size_t)(mbase + t) * 2048 + d]);
#pragma unroll
  for (int t = 0; t < CLEN; ++t) xv[t] = bf2f(xsb[(size_t)(mbase + t) * 2048 + d]);
#pragma unroll
  for (int t = 0; t < CLEN; ++t) zv[t] = bf2f(xzb[(size_t)(mbase + t) * 4096 + 2048 + d]);
  __syncthreads();
  for (int t = 0; t < CLEN; ++t) {
    float dx = dtv[t] * xv[t];
    float4 B0 = *(const float4*)&BCs[t][0];
    float4 B1 = *(const float4*)&BCs[t][4];
    float4 B2 = *(const float4*)&BCs[t][8];
    float4 B3 = *(const float4*)&BCs[t][12];
    float4 C0 = *(const float4*)&BCs[t][16];
    float4 C1 = *(const float4*)&BCs[t][20];
    float4 C2 = *(const float4*)&BCs[t][24];
    float4 C3 = *(const float4*)&BCs[t][28];
    const float* Bp[4] = {(const float*)&B0, (const float*)&B1, (const float*)&B2, (const float*)&B3};
    const float* Cp[4] = {(const float*)&C0, (const float*)&C1, (const float*)&C2, (const float*)&C3};
#pragma unroll
    for (int n = 0; n < 16; ++n)
      h[n] = __expf(dtv[t] * Ar[n]) * h[n] + dx * Bp[n >> 2][n & 3];
    float y0 = 0.f, y1 = 0.f, y2 = 0.f, y3 = 0.f;
#pragma unroll
    for (int n = 0; n < 4; ++n) {
      y0 += h[n]      * Cp[0][n];
      y1 += h[4 + n]  * Cp[1][n];
      y2 += h[8 + n]  * Cp[2][n];
      y3 += h[12 + n] * Cp[3][n];
    }
    float y = (y0 + y1) + (y2 + y3) + xv[t] * Dvd;
    float sz = zv[t] / (1.f + __expf(-zv[t]));
    yg[(size_t)(mbase + t) * 2048 + d] = f2bf(y * sz);
  }
}

// ---------------- head ----------------
__global__ __launch_bounds__(256) void final_ln_last_k(const float* __restrict__ xb,
    const float* __restrict__ w, const float* __restrict__ b, float* __restrict__ out) {
  int bb = blockIdx.x, tid = threadIdx.x;
  const float* x = xb + (size_t)(bb * 1024 + 1023) * 1024;
  float4 v = ((const float4*)x)[tid];
  float s = v.x + v.y + v.z + v.w;
  float q = v.x*v.x + v.y*v.y + v.z*v.z + v.w*v.w;
  for (int o = 32; o; o >>= 1) { s += __shfl_down(s, o); q += __shfl_down(q, o); }
  __shared__ float sb[4], qb[4];
  int wv = tid >> 6, lane = tid & 63;
  if (lane == 0) { sb[wv] = s; qb[wv] = q; }
  __syncthreads();
  s = sb[0] + sb[1] + sb[2] + sb[3];
  q = qb[0] + qb[1] + qb[2] + qb[3];
  float mean = s * (1.f / 1024.f);
  float rstd = rsqrtf(q * (1.f / 1024.f) - mean * mean + 1e-5f);
  float4 wv4 = ((const float4*)w)[tid];
  float4 bv4 = ((const float4*)b)[tid];
  float4 o;
  o.x = (v.x - mean) * rstd * wv4.x + bv4.x;
  o.y = (v.y - mean) * rstd * wv4.y + bv4.y;
  o.z = (v.z - mean) * rstd * wv4.z + bv4.z;
  o.w = (v.w - mean) * rstd * wv4.w + bv4.w;
  ((float4*)(out + bb * 1024))[tid] = o;
}

__global__ __launch_bounds__(256) void gemv_head1_k(const float* __restrict__ X,
    const float* __restrict__ W, const float* __restrict__ bias, float* __restrict__ out) {
  int gw = (blockIdx.x * 256 + threadIdx.x) >> 6;  // 0..4095
  int lane = threadIdx.x & 63;
  int b = gw >> 11, j = gw & 2047;
  const float* x = X + b * 1024;
  const float* w = W + (size_t)j * 1024;
  float s = 0.f;
#pragma unroll
  for (int q = 0; q < 4; ++q) {
    int col = q * 256 + lane * 4;
    float4 xv = *(const float4*)&x[col];
    float4 wv = *(const float4*)&w[col];
    s += xv.x*wv.x + xv.y*wv.y + xv.z*wv.z + xv.w*wv.w;
  }
  for (int o = 32; o; o >>= 1) s += __shfl_down(s, o);
  if (lane == 0) out[gw] = s + bias[j];
}

__global__ __launch_bounds__(256) void ln_gelu_k(const float* __restrict__ X,
    const float* __restrict__ w, const float* __restrict__ b, float* __restrict__ out) {
  int row = blockIdx.x, tid = threadIdx.x;
  const float* x = X + (size_t)row * 2048;
  float4 v0 = ((const float4*)x)[tid];
  float4 v1 = ((const float4*)x)[tid + 256];
  float s = v0.x+v0.y+v0.z+v0.w + v1.x+v1.y+v1.z+v1.w;
  float q = v0.x*v0.x+v0.y*v0.y+v0.z*v0.z+v0.w*v0.w
          + v1.x*v1.x+v1.y*v1.y+v1.z*v1.z+v1.w*v1.w;
  for (int o = 32; o; o >>= 1) { s += __shfl_down(s, o); q += __shfl_down(q, o); }
  __shared__ float sb[4], qb[4];
  int wv = tid >> 6, lane = tid & 63;
  if (lane == 0) { sb[wv] = s; qb[wv] = q; }
  __syncthreads();
  s = sb[0] + sb[1] + sb[2] + sb[3];
  q = qb[0] + qb[1] + qb[2] + qb[3];
  float mean = s * (1.f / 2048.f);
  float rstd = rsqrtf(q * (1.f / 2048.f) - mean * mean + 1e-5f);
  float* o0 = out + (size_t)row * 2048;
#pragma unroll
  for (int h = 0; h < 2; ++h) {
    float4 v = h ? v1 : v0;
    int c0 = tid * 4 + h * 1024;
    float4 wv4 = *(const float4*)&w[c0];
    float4 bv4 = *(const float4*)&b[c0];
    float4 g;
    g.x = (v.x - mean) * rstd * wv4.x + bv4.x;
    g.y = (v.y - mean) * rstd * wv4.y + bv4.y;
    g.z = (v.z - mean) * rstd * wv4.z + bv4.z;
    g.w = (v.w - mean) * rstd * wv4.w + bv4.w;
    g.x = 0.5f * g.x * (1.f + erff(g.x * 0.70710678f));
    g.y = 0.5f * g.y * (1.f + erff(g.y * 0.70710678f));
    g.z = 0.5f * g.z * (1.f + erff(g.z * 0.70710678f));
    g.w = 0.5f * g.w * (1.f + erff(g.w * 0.70710678f));
    *(float4*)&o0[c0] = g;
  }
}

__global__ __launch_bounds__(256) void gemv_head2_k(const float* __restrict__ X,
    const float* __restrict__ W, const float* __restrict__ bias, float* __restrict__ out) {
  int gw = (blockIdx.x * 256 + threadIdx.x) >> 6;  // 0..1999
  int lane = threadIdx.x & 63;
  int b = (gw >= 1000) ? 1 : 0;
  int j = gw - b * 1000;
  const float* x = X + b * 2048;
  const float* w = W + (size_t)j * 2048;
  float s = 0.f;
#pragma unroll
  for (int q = 0; q < 8; ++q) {
    int col = q * 256 + lane * 4;
    float4 xv = *(const float4*)&x[col];
    float4 wv = *(const float4*)&w[col];
    s += xv.x*wv.x + xv.y*wv.y + xv.z*wv.z + xv.w*wv.w;
  }
  for (int o = 32; o; o >>= 1) s += __shfl_down(s, o);
  if (lane == 0) out[gw] = s + bias[j];
}

// ---------------- launch ----------------
extern "C" void kernel_launch(void* const* d_in, const int* in_sizes, int n_in,
                              void* d_out, int out_size, void* d_ws, size_t ws_size,
                              hipStream_t stream) {
  const float* x_in = (const float*)d_in[0];
  const float* lnw  = (const float*)d_in[1];
  const float* lnb  = (const float*)d_in[2];
  const float* ipw  = (const float*)d_in[3];
  const float* cw   = (const float*)d_in[4];
  const float* cb   = (const float*)d_in[5];
  const float* xpw  = (const float*)d_in[6];
  const float* dpw  = (const float*)d_in[7];
  const float* dpb  = (const float*)d_in[8];
  const float* Alog = (const float*)d_in[9];
  const float* Dv   = (const float*)d_in[10];
  const float* opw  = (const float*)d_in[11];
  const float* fnw  = (const float*)d_in[12];
  const float* fnb  = (const float*)d_in[13];
  const float* h1w  = (const float*)d_in[14];
  const float* h1b  = (const float*)d_in[15];
  const float* hlnw = (const float*)d_in[16];
  const float* hlnb = (const float*)d_in[17];
  const float* h2w  = (const float*)d_in[18];
  const float* h2b  = (const float*)d_in[19];
  float* out = (float*)d_out;

  char* ws = (char*)d_ws;
  size_t off = 0;
  auto alloc = [&](size_t bytes) -> void* {
    void* p = ws + off; off += (bytes + 255) & ~(size_t)255; return p;
  };
  float* x_buf   = (float*)alloc((size_t)MTOK * DMODEL * 4);
  u16*   xn_bf   = (u16*)  alloc((size_t)MTOK * DMODEL * 2);
  u16*   xz_bf   = (u16*)  alloc((size_t)MTOK * 2 * DINNER * 2);
  u16*   xs_bf   = (u16*)  alloc((size_t)MTOK * DINNER * 2);
  float* xdbl4   = (float*)alloc((size_t)NLAYER * MTOK * 128 * 4);
  u16*   dtb     = (u16*)  alloc((size_t)MTOK * DINNER * 2);
  u16*   yg_bf   = (u16*)  alloc((size_t)MTOK * DINNER * 2);
  u16*   w_ip4   = (u16*)  alloc((size_t)NLAYER * 2 * DINNER * DMODEL * 2);
  u16*   w_xp4   = (u16*)  alloc((size_t)NLAYER * 128 * DINNER * 2);
  u16*   w_dt4   = (u16*)  alloc((size_t)NLAYER * DINNER * DTRANK * 2);
  u16*   w_op4   = (u16*)  alloc((size_t)NLAYER * DMODEL * DINNER * 2);
  float* PS      = (float*)alloc((size_t)NBATCH * NCH * DINNER * 32 * 4);
  float* Hstart  = (float*)alloc((size_t)NBATCH * NCH * DINNER * 16 * 4);
  float* lastn   = (float*)alloc(2 * 1024 * 4);
  float* hpre    = (float*)alloc(2 * 2048 * 4);
  float* hbuf    = (float*)alloc(2 * 2048 * 4);

  hipMemcpyAsync(x_buf, x_in, (size_t)MTOK * DMODEL * 4, hipMemcpyDeviceToDevice, stream);
  { dim3 g(4096, 4); f32_to_bf16_l<<<g, 256, 0, stream>>>(ipw, w_ip4, 2 * DINNER * DMODEL); }
  { dim3 g(256, 4);  cvt_pad_xproj_l<<<g, 256, 0, stream>>>(xpw, w_xp4); }
  { dim3 g(128, 4);  f32_to_bf16_l<<<g, 256, 0, stream>>>(dpw, w_dt4, DINNER * DTRANK); }
  { dim3 g(2048, 4); f32_to_bf16_l<<<g, 256, 0, stream>>>(opw, w_op4, DMODEL * DINNER); }
  hipMemsetAsync(xdbl4, 0, (size_t)NLAYER * MTOK * 128 * 4, stream);

  for (int i = 0; i < NLAYER; ++i) {
    float* xdbl_l = xdbl4 + (size_t)i * MTOK * 128;
    ln_to_bf16_k<<<MTOK, 256, 0, stream>>>(x_buf, lnw + i * DMODEL, lnb + i * DMODEL, xn_bf);
    { dim3 g(16, 32, 1);
      gemm_bt<1><<<g, 256, 0, stream>>>(xn_bf, w_ip4 + (size_t)i * 2 * DINNER * DMODEL,
                                        (float*)xz_bf, 1024, 1024, 4096, 1024); }
    conv_silu_k<<<4096, 256, 0, stream>>>(xz_bf, cw + (size_t)i * DINNER * 4, cb + i * DINNER, xs_bf);
    { dim3 g(16, 1, 8);
      gemm_bt<3><<<g, 256, 0, stream>>>(xs_bf, w_xp4 + (size_t)i * 128 * DINNER,
                                        xdbl_l, 2048, 2048, 128, 256); }
    { dim3 g(16, 16, 1);
      gemm_dt_k<<<g, 256, 0, stream>>>(xdbl_l, w_dt4 + (size_t)i * DINNER * DTRANK,
                                       dpb + i * DINNER, dtb); }
    scan_part1<<<1024, 256, 0, stream>>>(dtb, xs_bf, xdbl_l, Alog + (size_t)i * DINNER * DSTATE, PS);
    scan_prefix<<<256, 256, 0, stream>>>(PS, Hstart);
    scan_part2<<<1024, 256, 0, stream>>>(dtb, xs_bf, xdbl_l, Alog + (size_t)i * DINNER * DSTATE,
                                         Dv + i * DINNER, xz_bf, Hstart, yg_bf);
    { dim3 g(16, 8, 2);
      gemm_bt<3><<<g, 256, 0, stream>>>(yg_bf, w_op4 + (size_t)i * DMODEL * DINNER,
                                        x_buf, 2048, 2048, 1024, 1024); }
  }
  final_ln_last_k<<<2, 256, 0, stream>>>(x_buf, fnw, fnb, lastn);
  gemv_head1_k<<<1024, 256, 0, stream>>>(lastn, h1w, h1b, hpre);
  ln_gelu_k<<<2, 256, 0, stream>>>(hpre, hlnw, hlnb, hbuf);
  gemv_head2_k<<<500, 256, 0, stream>>>(hbuf, h2w, h2b, out);
  (void)in_sizes; (void)n_in; (void)out_size; (void)ws_size;
}